// Round 1
// baseline (456.359 us; speedup 1.0000x reference)
//
#include <hip/hip_runtime.h>
#include <hip/hip_bf16.h>
#include <math.h>

#define NB 4
#define CC 128
#define HH 64
#define WW 64
#define HEADS 4
#define KS 7
#define DD 32
#define HW 4096
#define MTOT 16384   // NB*HW

__device__ __forceinline__ float gelu_f(float x) {
    return 0.5f * x * (1.0f + erff(x * 0.70710678118654752440f));
}

// ---------------- block reduce (128 threads = 2 waves) ----------------
__device__ __forceinline__ float block_sum_128(float v, float* tmp) {
    #pragma unroll
    for (int off = 32; off; off >>= 1) v += __shfl_xor(v, off);
    __syncthreads();
    if ((threadIdx.x & 63) == 0) tmp[threadIdx.x >> 6] = v;
    __syncthreads();
    return tmp[0] + tmp[1];
}

// ---------------- LN1: read NCHW, write NHWC row-major (M,128) --------
__global__ __launch_bounds__(128) void ln1_kernel(
    const float* __restrict__ x, const float* __restrict__ w,
    const float* __restrict__ b, float* __restrict__ out)
{
    __shared__ float tmp[2];
    int m = blockIdx.x;            // 0..16383
    int c = threadIdx.x;
    int n = m >> 12;
    int p = m & 4095;
    float v = x[(size_t)(n * CC + c) * HW + p];
    float mu = block_sum_128(v, tmp) * (1.0f / CC);
    float d = v - mu;
    float var = block_sum_128(d * d, tmp) * (1.0f / CC);
    float r = rsqrtf(var + 1e-5f);
    out[(size_t)m * CC + c] = d * r * w[c] + b[c];
}

// ---------------- LN over contiguous rows (M,128) ---------------------
__global__ __launch_bounds__(128) void ln_rows_kernel(
    const float* __restrict__ in, const float* __restrict__ w,
    const float* __restrict__ b, float* __restrict__ out)
{
    __shared__ float tmp[2];
    int m = blockIdx.x;
    int c = threadIdx.x;
    float v = in[(size_t)m * CC + c];
    float mu = block_sum_128(v, tmp) * (1.0f / CC);
    float d = v - mu;
    float var = block_sum_128(d * d, tmp) * (1.0f / CC);
    float r = rsqrtf(var + 1e-5f);
    out[(size_t)m * CC + c] = d * r * w[c] + b[c];
}

// ---------------- generic tiled fp32 GEMM: C = act(A@B + bias) --------
// A (M,K) row-major, B (K,N) row-major, bias (N). ACT: 0=none, 1=gelu
#define BM 64
#define BN 64
#define BK 16
template<int ACT>
__global__ __launch_bounds__(256) void gemm_bias_act(
    const float* __restrict__ A, const float* __restrict__ B,
    const float* __restrict__ bias, float* __restrict__ C,
    int M, int Nn, int K)
{
    __shared__ float As[BK][BM + 1];   // As[k][m]
    __shared__ float Bs[BK][BN + 1];   // Bs[k][n]
    int tid = threadIdx.x;
    int row0 = blockIdx.y * BM;
    int col0 = blockIdx.x * BN;
    int tr = tid >> 4;   // 0..15 -> 4 rows each
    int tc = tid & 15;   // 0..15 -> 4 cols each

    float acc[4][4] = {};
    const bool full_n = (col0 + BN <= Nn);

    for (int k0 = 0; k0 < K; k0 += BK) {
        {   // A tile: 64x16, float4 per thread
            int r = tid >> 2;
            int c = (tid & 3) << 2;
            const float4 av = *(const float4*)(A + (size_t)(row0 + r) * K + k0 + c);
            As[c + 0][r] = av.x; As[c + 1][r] = av.y;
            As[c + 2][r] = av.z; As[c + 3][r] = av.w;
        }
        {   // B tile: 16x64
            int r = tid >> 4;
            int cb = (tid & 15) << 2;
            if (full_n) {
                const float4 bv = *(const float4*)(B + (size_t)(k0 + r) * Nn + col0 + cb);
                Bs[r][cb + 0] = bv.x; Bs[r][cb + 1] = bv.y;
                Bs[r][cb + 2] = bv.z; Bs[r][cb + 3] = bv.w;
            } else {
                #pragma unroll
                for (int u = 0; u < 4; u++) {
                    int c = cb + u;
                    Bs[r][c] = (col0 + c < Nn) ? B[(size_t)(k0 + r) * Nn + col0 + c] : 0.f;
                }
            }
        }
        __syncthreads();
        #pragma unroll
        for (int kk = 0; kk < BK; kk++) {
            float a0 = As[kk][tr * 4 + 0], a1 = As[kk][tr * 4 + 1];
            float a2 = As[kk][tr * 4 + 2], a3 = As[kk][tr * 4 + 3];
            float b0 = Bs[kk][tc * 4 + 0], b1 = Bs[kk][tc * 4 + 1];
            float b2 = Bs[kk][tc * 4 + 2], b3 = Bs[kk][tc * 4 + 3];
            acc[0][0] += a0 * b0; acc[0][1] += a0 * b1; acc[0][2] += a0 * b2; acc[0][3] += a0 * b3;
            acc[1][0] += a1 * b0; acc[1][1] += a1 * b1; acc[1][2] += a1 * b2; acc[1][3] += a1 * b3;
            acc[2][0] += a2 * b0; acc[2][1] += a2 * b1; acc[2][2] += a2 * b2; acc[2][3] += a2 * b3;
            acc[3][0] += a3 * b0; acc[3][1] += a3 * b1; acc[3][2] += a3 * b2; acc[3][3] += a3 * b3;
        }
        __syncthreads();
    }

    #pragma unroll
    for (int i = 0; i < 4; i++) {
        int row = row0 + tr * 4 + i;
        #pragma unroll
        for (int j = 0; j < 4; j++) {
            int col = col0 + tc * 4 + j;
            if (col < Nn) {
                float v = acc[i][j] + bias[col];
                if (ACT == 1) v = gelu_f(v);
                C[(size_t)row * Nn + col] = v;
            }
        }
    }
}

// ---------------- HW-mean partials: t (M,128) -> part (4*32,128) ------
__global__ __launch_bounds__(128) void mean_partial_kernel(
    const float* __restrict__ t, float* __restrict__ part)
{
    int blk = blockIdx.x;          // 0..127 = n*32 + chunk
    int n = blk >> 5;
    int chunk = blk & 31;
    int c = threadIdx.x;
    float s = 0.f;
    int base = n * HW + chunk * 128;
    for (int r = 0; r < 128; r++)
        s += t[(size_t)(base + r) * CC + c];
    part[(size_t)blk * CC + c] = s;
}

// ---------------- channel-attention tiny MLP --------------------------
__global__ __launch_bounds__(128) void ca_kernel(
    const float* __restrict__ part,
    const float* __restrict__ ca1_w, const float* __restrict__ ca1_b,
    const float* __restrict__ ca2_w, const float* __restrict__ ca2_b,
    float* __restrict__ g2)
{
    __shared__ float gs[128];
    __shared__ float h1[7];
    int n = blockIdx.x;
    int c = threadIdx.x;
    float s = 0.f;
    for (int k = 0; k < 32; k++) s += part[(size_t)(n * 32 + k) * CC + c];
    float gm = s * (1.0f / HW);
    gs[c] = gm;
    __syncthreads();
    if (c < 7) {
        float a = ca1_b[c];
        for (int k = 0; k < 128; k++) a += gs[k] * ca1_w[k * 7 + c];
        h1[c] = fmaxf(a, 0.f);
    }
    __syncthreads();
    float o = ca2_b[c];
    #pragma unroll
    for (int r = 0; r < 7; r++) o += h1[r] * ca2_w[r * 128 + c];
    g2[(size_t)n * CC + c] = 1.0f / (1.0f + expf(-o));
}

// ---------------- neighborhood attention ------------------------------
// qkv (M, 384): [s*128 + h*32 + d]. out (M, 128). one block per pixel,
// one wave (64 lanes) per head.
__global__ __launch_bounds__(256) void na_attn_kernel(
    const float* __restrict__ qkv, const float* __restrict__ rpb,
    float* __restrict__ out)
{
    __shared__ float sattn[HEADS][64];
    int m = blockIdx.x;
    int n = m >> 12;
    int ij = m & 4095;
    int i = ij >> 6, j = ij & 63;
    int h = threadIdx.x >> 6;
    int lane = threadIdx.x & 63;

    int ni = min(max(i - 3, 0), HH - KS);
    int nj = min(max(j - 3, 0), WW - KS);

    const float* qrow = qkv + (size_t)m * 384 + h * DD;
    float score = -INFINITY;
    if (lane < KS * KS) {
        int a = lane / KS, b = lane % KS;
        int ki = ni + a, kj = nj + b;
        const float* krow = qkv + ((size_t)((n * HH + ki) * WW + kj)) * 384 + 128 + h * DD;
        float s = 0.f;
        #pragma unroll
        for (int d = 0; d < DD; d++) s += qrow[d] * krow[d];
        s *= 0.17677669529663688110f;     // 1/sqrt(32)
        s += rpb[(h * 13 + (ki - i + 6)) * 13 + (kj - j + 6)];
        score = s;
    }
    float mx = score;
    #pragma unroll
    for (int off = 32; off; off >>= 1) mx = fmaxf(mx, __shfl_xor(mx, off));
    float e = (lane < KS * KS) ? expf(score - mx) : 0.f;
    float sm = e;
    #pragma unroll
    for (int off = 32; off; off >>= 1) sm += __shfl_xor(sm, off);
    sattn[h][lane] = e / sm;
    __syncthreads();

    if (lane < DD) {
        float acc = 0.f;
        #pragma unroll 7
        for (int a = 0; a < KS * KS; a++) {
            int ki = ni + a / KS, kj = nj + a % KS;
            const float* vrow = qkv + ((size_t)((n * HH + ki) * WW + kj)) * 384 + 256 + h * DD;
            acc += sattn[h][a] * vrow[lane];
        }
        out[(size_t)m * CC + h * DD + lane] = acc;
    }
}

// ---------------- x2 = shortcut + proj_out + 0.02 * t * g -------------
__global__ __launch_bounds__(128) void x2_kernel(
    const float* __restrict__ x, const float* __restrict__ projout,
    const float* __restrict__ t, const float* __restrict__ g2,
    float* __restrict__ x2)
{
    int m = blockIdx.x;
    int c = threadIdx.x;
    int n = m >> 12;
    int p = m & 4095;
    float sc = x[(size_t)(n * CC + c) * HW + p];
    size_t idx = (size_t)m * CC + c;
    x2[idx] = sc + projout[idx] + 0.02f * t[idx] * g2[(size_t)n * CC + c];
}

// ---------------- out NCHW = x2 + m -----------------------------------
__global__ __launch_bounds__(128) void final_kernel(
    const float* __restrict__ x2, const float* __restrict__ mo,
    float* __restrict__ out)
{
    int m = blockIdx.x;
    int c = threadIdx.x;
    int n = m >> 12;
    int p = m & 4095;
    size_t idx = (size_t)m * CC + c;
    out[(size_t)(n * CC + c) * HW + p] = x2[idx] + mo[idx];
}

extern "C" void kernel_launch(void* const* d_in, const int* in_sizes, int n_in,
                              void* d_out, int out_size, void* d_ws, size_t ws_size,
                              hipStream_t stream)
{
    const float* x       = (const float*)d_in[0];
    const float* ln1_w   = (const float*)d_in[1];
    const float* ln1_b   = (const float*)d_in[2];
    const float* ln2_w   = (const float*)d_in[3];
    const float* ln2_b   = (const float*)d_in[4];
    const float* qkv_w   = (const float*)d_in[5];
    const float* qkv_b   = (const float*)d_in[6];
    const float* proj_w  = (const float*)d_in[7];
    const float* proj_b  = (const float*)d_in[8];
    const float* rpb     = (const float*)d_in[9];
    const float* conv1_w = (const float*)d_in[10];
    const float* conv1_b = (const float*)d_in[11];
    const float* conv2_w = (const float*)d_in[12];
    const float* conv2_b = (const float*)d_in[13];
    const float* ca1_w   = (const float*)d_in[14];
    const float* ca1_b   = (const float*)d_in[15];
    const float* ca2_w   = (const float*)d_in[16];
    const float* ca2_b   = (const float*)d_in[17];
    const float* fc1_w   = (const float*)d_in[18];
    const float* fc1_b   = (const float*)d_in[19];
    const float* fc2_w   = (const float*)d_in[20];
    const float* fc2_b   = (const float*)d_in[21];
    float* out = (float*)d_out;

    // workspace layout (floats). hbuf (M*512) overlays xn+qkv (dead by fc1).
    float* f0   = (float*)d_ws;
    float* xn   = f0;                       // M*128 = 2,097,152
    float* qkv  = f0 + 2097152;             // M*384 = 6,291,456
    float* hbuf = f0;                       // M*512 = 8,388,608 (overlay)
    float* t    = f0 + 8388608;             // M*128
    float* na   = f0 + 10485760;            // M*128  (later: fc2 out)
    float* pe   = f0 + 12582912;            // M*128  (proj out, later ln2 out)
    float* x2b  = f0 + 14680064;            // M*128
    float* part = f0 + 16777216;            // 128*128 = 16,384
    float* g2   = f0 + 16793600;            // 512
    float* c1   = f0 + 16794112;            // M*32 = 524,288
    float* mo   = na;

    // 1. LN1 (NCHW -> NHWC rows)
    ln1_kernel<<<MTOT, 128, 0, stream>>>(x, ln1_w, ln1_b, xn);
    // 2. conv1: (M,128)@(128,32) + gelu
    gemm_bias_act<1><<<dim3(1, MTOT / BM), 256, 0, stream>>>(xn, conv1_w, conv1_b, c1, MTOT, 32, 128);
    // 3. conv2: (M,32)@(32,128)
    gemm_bias_act<0><<<dim3(2, MTOT / BM), 256, 0, stream>>>(c1, conv2_w, conv2_b, t, MTOT, 128, 32);
    // 4-5. channel attention gate
    mean_partial_kernel<<<128, 128, 0, stream>>>(t, part);
    ca_kernel<<<NB, 128, 0, stream>>>(part, ca1_w, ca1_b, ca2_w, ca2_b, g2);
    // 6. qkv: (M,128)@(128,384)
    gemm_bias_act<0><<<dim3(6, MTOT / BM), 256, 0, stream>>>(xn, qkv_w, qkv_b, qkv, MTOT, 384, 128);
    // 7. neighborhood attention
    na_attn_kernel<<<MTOT, 256, 0, stream>>>(qkv, rpb, na);
    // 8. proj: (M,128)@(128,128)
    gemm_bias_act<0><<<dim3(2, MTOT / BM), 256, 0, stream>>>(na, proj_w, proj_b, pe, MTOT, 128, 128);
    // 9. residual + gated conv branch
    x2_kernel<<<MTOT, 128, 0, stream>>>(x, pe, t, g2, x2b);
    // 10. LN2 (rows), write into pe (proj out dead)
    ln_rows_kernel<<<MTOT, 128, 0, stream>>>(x2b, ln2_w, ln2_b, pe);
    // 11. fc1: (M,128)@(128,512) + gelu  -> hbuf (overlays xn+qkv, both dead)
    gemm_bias_act<1><<<dim3(8, MTOT / BM), 256, 0, stream>>>(pe, fc1_w, fc1_b, hbuf, MTOT, 512, 128);
    // 12. fc2: (M,512)@(512,128) -> mo (overlays na, dead)
    gemm_bias_act<0><<<dim3(2, MTOT / BM), 256, 0, stream>>>(hbuf, fc2_w, fc2_b, mo, MTOT, 128, 512);
    // 13. final residual + NHWC->NCHW
    final_kernel<<<MTOT, 128, 0, stream>>>(x2b, mo, out);
}

// Round 2
// 347.091 us; speedup vs baseline: 1.3148x; 1.3148x over previous
//
#include <hip/hip_runtime.h>
#include <hip/hip_bf16.h>
#include <math.h>

#define NB 4
#define CC 128
#define HH 64
#define WW 64
#define HEADS 4
#define KS 7
#define DD 32
#define HW 4096
#define MTOT 16384   // NB*HW

typedef short short8 __attribute__((ext_vector_type(8)));
typedef float floatx4 __attribute__((ext_vector_type(4)));

__device__ __forceinline__ float gelu_f(float x) {
    return 0.5f * x * (1.0f + erff(x * 0.70710678118654752440f));
}

__device__ __forceinline__ unsigned short f2bf(float f) {
    union { float f; unsigned u; } a; a.f = f;
    unsigned u = a.u;
    unsigned r = u + 0x7FFFu + ((u >> 16) & 1u);   // RNE
    return (unsigned short)(r >> 16);
}

// ---------------- block reduce (128 threads = 2 waves) ----------------
__device__ __forceinline__ float block_sum_128(float v, float* tmp) {
    #pragma unroll
    for (int off = 32; off; off >>= 1) v += __shfl_xor(v, off);
    __syncthreads();
    if ((threadIdx.x & 63) == 0) tmp[threadIdx.x >> 6] = v;
    __syncthreads();
    return tmp[0] + tmp[1];
}

// ---------------- LN1: read NCHW, write NHWC row-major (M,128) --------
__global__ __launch_bounds__(128) void ln1_kernel(
    const float* __restrict__ x, const float* __restrict__ w,
    const float* __restrict__ b, float* __restrict__ out)
{
    __shared__ float tmp[2];
    int m = blockIdx.x;            // 0..16383
    int c = threadIdx.x;
    int n = m >> 12;
    int p = m & 4095;
    float v = x[(size_t)(n * CC + c) * HW + p];
    float mu = block_sum_128(v, tmp) * (1.0f / CC);
    float d = v - mu;
    float var = block_sum_128(d * d, tmp) * (1.0f / CC);
    float r = rsqrtf(var + 1e-5f);
    out[(size_t)m * CC + c] = d * r * w[c] + b[c];
}

// ---------------- LN over contiguous rows (M,128) ---------------------
__global__ __launch_bounds__(128) void ln_rows_kernel(
    const float* __restrict__ in, const float* __restrict__ w,
    const float* __restrict__ b, float* __restrict__ out)
{
    __shared__ float tmp[2];
    int m = blockIdx.x;
    int c = threadIdx.x;
    float v = in[(size_t)m * CC + c];
    float mu = block_sum_128(v, tmp) * (1.0f / CC);
    float d = v - mu;
    float var = block_sum_128(d * d, tmp) * (1.0f / CC);
    float r = rsqrtf(var + 1e-5f);
    out[(size_t)m * CC + c] = d * r * w[c] + b[c];
}

// ---------------- bf16 MFMA GEMM: C = act(A@B + bias) -----------------
// A (M,K) fp32 row-major, B (K,N) fp32 row-major, bias (N), C fp32.
// BM=128, BN=64, BK=32. 256 threads = 4 waves; wave w -> rows [32w,32w+32)
// as 2 m-tiles x 4 n-tiles of 16x16 mfma. K must be a multiple of 32.
// Fragment maps (m89/m91-verified): A[m=lane&15][k=q*8+j],
// B[k=q*8+j][n=lane&15], C/D row=q*4+reg, col=lane&15.
#define BM 128
#define BN 64
#define BK 32
#define LDK 40   // padded LDS row (bf16 elems); 80B stride, 16B-aligned
template<int ACT>
__global__ __launch_bounds__(256) void gemm_mfma(
    const float* __restrict__ A, const float* __restrict__ B,
    const float* __restrict__ bias, float* __restrict__ C,
    int M, int N, int K)
{
    __shared__ __align__(16) unsigned short Alds[BM][LDK];
    __shared__ __align__(16) unsigned short Blds[BN][LDK];   // transposed: [n][k]

    const int t    = threadIdx.x;
    const int w    = t >> 6;
    const int lane = t & 63;
    const int q    = lane >> 4;
    const int r16  = lane & 15;
    const int row0 = blockIdx.y * BM;
    const int col0 = blockIdx.x * BN;

    floatx4 acc[2][4] = {};

    // staging coords
    const int ar = t >> 1;             // A row 0..127
    const int ak = (t & 1) * 16;       // A k offset {0,16}
    const int bk = t >> 3;             // B k row 0..31
    const int bn = (t & 7) * 8;        // B n offset 0..56

    for (int k0 = 0; k0 < K; k0 += BK) {
        // ---- stage A: 128x32 fp32 -> bf16, [row][k] ----
        {
            const float* src = A + (size_t)(row0 + ar) * K + k0 + ak;
            float4 v0 = *(const float4*)(src);
            float4 v1 = *(const float4*)(src + 4);
            float4 v2 = *(const float4*)(src + 8);
            float4 v3 = *(const float4*)(src + 12);
            short8 s0, s1;
            s0[0] = f2bf(v0.x); s0[1] = f2bf(v0.y); s0[2] = f2bf(v0.z); s0[3] = f2bf(v0.w);
            s0[4] = f2bf(v1.x); s0[5] = f2bf(v1.y); s0[6] = f2bf(v1.z); s0[7] = f2bf(v1.w);
            s1[0] = f2bf(v2.x); s1[1] = f2bf(v2.y); s1[2] = f2bf(v2.z); s1[3] = f2bf(v2.w);
            s1[4] = f2bf(v3.x); s1[5] = f2bf(v3.y); s1[6] = f2bf(v3.z); s1[7] = f2bf(v3.w);
            *(short8*)(&Alds[ar][ak])     = s0;
            *(short8*)(&Alds[ar][ak + 8]) = s1;
        }
        // ---- stage B: 32x64 fp32 -> bf16, transposed [n][k] ----
        {
            const float* src = B + (size_t)(k0 + bk) * N + col0 + bn;
            if (col0 + bn + 8 <= N) {
                float4 b0 = *(const float4*)(src);
                float4 b1 = *(const float4*)(src + 4);
                Blds[bn + 0][bk] = f2bf(b0.x); Blds[bn + 1][bk] = f2bf(b0.y);
                Blds[bn + 2][bk] = f2bf(b0.z); Blds[bn + 3][bk] = f2bf(b0.w);
                Blds[bn + 4][bk] = f2bf(b1.x); Blds[bn + 5][bk] = f2bf(b1.y);
                Blds[bn + 6][bk] = f2bf(b1.z); Blds[bn + 7][bk] = f2bf(b1.w);
            } else {
                #pragma unroll
                for (int u = 0; u < 8; u++) {
                    int col = col0 + bn + u;
                    Blds[bn + u][bk] = (col < N) ? f2bf(src[u]) : (unsigned short)0;
                }
            }
        }
        __syncthreads();

        short8 af[2], bf[4];
        #pragma unroll
        for (int mt = 0; mt < 2; mt++)
            af[mt] = *(const short8*)(&Alds[w * 32 + mt * 16 + r16][q * 8]);
        #pragma unroll
        for (int nt = 0; nt < 4; nt++)
            bf[nt] = *(const short8*)(&Blds[nt * 16 + r16][q * 8]);

        #pragma unroll
        for (int mt = 0; mt < 2; mt++)
            #pragma unroll
            for (int nt = 0; nt < 4; nt++)
                acc[mt][nt] = __builtin_amdgcn_mfma_f32_16x16x32_bf16(
                    af[mt], bf[nt], acc[mt][nt], 0, 0, 0);
        __syncthreads();
    }

    // ---- epilogue: bias + act, fp32 store ----
    #pragma unroll
    for (int mt = 0; mt < 2; mt++) {
        #pragma unroll
        for (int nt = 0; nt < 4; nt++) {
            int col = col0 + nt * 16 + r16;
            if (col < N) {
                float bv = bias[col];
                #pragma unroll
                for (int reg = 0; reg < 4; reg++) {
                    int row = row0 + w * 32 + mt * 16 + q * 4 + reg;
                    float v = acc[mt][nt][reg] + bv;
                    if (ACT == 1) v = gelu_f(v);
                    C[(size_t)row * N + col] = v;
                }
            }
        }
    }
}

// ---------------- HW-mean partials: t (M,128) -> part (4*32,128) ------
__global__ __launch_bounds__(128) void mean_partial_kernel(
    const float* __restrict__ t, float* __restrict__ part)
{
    int blk = blockIdx.x;          // 0..127 = n*32 + chunk
    int n = blk >> 5;
    int chunk = blk & 31;
    int c = threadIdx.x;
    float s = 0.f;
    int base = n * HW + chunk * 128;
    for (int r = 0; r < 128; r++)
        s += t[(size_t)(base + r) * CC + c];
    part[(size_t)blk * CC + c] = s;
}

// ---------------- channel-attention tiny MLP --------------------------
__global__ __launch_bounds__(128) void ca_kernel(
    const float* __restrict__ part,
    const float* __restrict__ ca1_w, const float* __restrict__ ca1_b,
    const float* __restrict__ ca2_w, const float* __restrict__ ca2_b,
    float* __restrict__ g2)
{
    __shared__ float gs[128];
    __shared__ float h1[7];
    int n = blockIdx.x;
    int c = threadIdx.x;
    float s = 0.f;
    for (int k = 0; k < 32; k++) s += part[(size_t)(n * 32 + k) * CC + c];
    float gm = s * (1.0f / HW);
    gs[c] = gm;
    __syncthreads();
    if (c < 7) {
        float a = ca1_b[c];
        for (int k = 0; k < 128; k++) a += gs[k] * ca1_w[k * 7 + c];
        h1[c] = fmaxf(a, 0.f);
    }
    __syncthreads();
    float o = ca2_b[c];
    #pragma unroll
    for (int r = 0; r < 7; r++) o += h1[r] * ca2_w[r * 128 + c];
    g2[(size_t)n * CC + c] = 1.0f / (1.0f + expf(-o));
}

// ---------------- neighborhood attention ------------------------------
// qkv (M, 384): [s*128 + h*32 + d]. out (M, 128). one block per pixel,
// one wave (64 lanes) per head.
__global__ __launch_bounds__(256) void na_attn_kernel(
    const float* __restrict__ qkv, const float* __restrict__ rpb,
    float* __restrict__ out)
{
    __shared__ float sattn[HEADS][64];
    int m = blockIdx.x;
    int n = m >> 12;
    int ij = m & 4095;
    int i = ij >> 6, j = ij & 63;
    int h = threadIdx.x >> 6;
    int lane = threadIdx.x & 63;

    int ni = min(max(i - 3, 0), HH - KS);
    int nj = min(max(j - 3, 0), WW - KS);

    const float* qrow = qkv + (size_t)m * 384 + h * DD;
    float score = -INFINITY;
    if (lane < KS * KS) {
        int a = lane / KS, b = lane % KS;
        int ki = ni + a, kj = nj + b;
        const float* krow = qkv + ((size_t)((n * HH + ki) * WW + kj)) * 384 + 128 + h * DD;
        float s = 0.f;
        #pragma unroll
        for (int d = 0; d < DD; d++) s += qrow[d] * krow[d];
        s *= 0.17677669529663688110f;     // 1/sqrt(32)
        s += rpb[(h * 13 + (ki - i + 6)) * 13 + (kj - j + 6)];
        score = s;
    }
    float mx = score;
    #pragma unroll
    for (int off = 32; off; off >>= 1) mx = fmaxf(mx, __shfl_xor(mx, off));
    float e = (lane < KS * KS) ? expf(score - mx) : 0.f;
    float sm = e;
    #pragma unroll
    for (int off = 32; off; off >>= 1) sm += __shfl_xor(sm, off);
    sattn[h][lane] = e / sm;
    __syncthreads();

    if (lane < DD) {
        float acc = 0.f;
        #pragma unroll 7
        for (int a = 0; a < KS * KS; a++) {
            int ki = ni + a / KS, kj = nj + a % KS;
            const float* vrow = qkv + ((size_t)((n * HH + ki) * WW + kj)) * 384 + 256 + h * DD;
            acc += sattn[h][a] * vrow[lane];
        }
        out[(size_t)m * CC + h * DD + lane] = acc;
    }
}

// ---------------- x2 = shortcut + proj_out + 0.02 * t * g -------------
__global__ __launch_bounds__(128) void x2_kernel(
    const float* __restrict__ x, const float* __restrict__ projout,
    const float* __restrict__ t, const float* __restrict__ g2,
    float* __restrict__ x2)
{
    int m = blockIdx.x;
    int c = threadIdx.x;
    int n = m >> 12;
    int p = m & 4095;
    float sc = x[(size_t)(n * CC + c) * HW + p];
    size_t idx = (size_t)m * CC + c;
    x2[idx] = sc + projout[idx] + 0.02f * t[idx] * g2[(size_t)n * CC + c];
}

// ---------------- out NCHW = x2 + m -----------------------------------
__global__ __launch_bounds__(128) void final_kernel(
    const float* __restrict__ x2, const float* __restrict__ mo,
    float* __restrict__ out)
{
    int m = blockIdx.x;
    int c = threadIdx.x;
    int n = m >> 12;
    int p = m & 4095;
    size_t idx = (size_t)m * CC + c;
    out[(size_t)(n * CC + c) * HW + p] = x2[idx] + mo[idx];
}

extern "C" void kernel_launch(void* const* d_in, const int* in_sizes, int n_in,
                              void* d_out, int out_size, void* d_ws, size_t ws_size,
                              hipStream_t stream)
{
    const float* x       = (const float*)d_in[0];
    const float* ln1_w   = (const float*)d_in[1];
    const float* ln1_b   = (const float*)d_in[2];
    const float* ln2_w   = (const float*)d_in[3];
    const float* ln2_b   = (const float*)d_in[4];
    const float* qkv_w   = (const float*)d_in[5];
    const float* qkv_b   = (const float*)d_in[6];
    const float* proj_w  = (const float*)d_in[7];
    const float* proj_b  = (const float*)d_in[8];
    const float* rpb     = (const float*)d_in[9];
    const float* conv1_w = (const float*)d_in[10];
    const float* conv1_b = (const float*)d_in[11];
    const float* conv2_w = (const float*)d_in[12];
    const float* conv2_b = (const float*)d_in[13];
    const float* ca1_w   = (const float*)d_in[14];
    const float* ca1_b   = (const float*)d_in[15];
    const float* ca2_w   = (const float*)d_in[16];
    const float* ca2_b   = (const float*)d_in[17];
    const float* fc1_w   = (const float*)d_in[18];
    const float* fc1_b   = (const float*)d_in[19];
    const float* fc2_w   = (const float*)d_in[20];
    const float* fc2_b   = (const float*)d_in[21];
    float* out = (float*)d_out;

    // workspace layout (floats). hbuf (M*512) overlays xn+qkv (dead by fc1).
    float* f0   = (float*)d_ws;
    float* xn   = f0;                       // M*128 = 2,097,152
    float* qkv  = f0 + 2097152;             // M*384 = 6,291,456
    float* hbuf = f0;                       // M*512 = 8,388,608 (overlay)
    float* t    = f0 + 8388608;             // M*128
    float* na   = f0 + 10485760;            // M*128  (later: fc2 out)
    float* pe   = f0 + 12582912;            // M*128  (proj out, later ln2 out)
    float* x2b  = f0 + 14680064;            // M*128
    float* part = f0 + 16777216;            // 128*128 = 16,384
    float* g2   = f0 + 16793600;            // 512
    float* c1   = f0 + 16794112;            // M*32 = 524,288
    float* mo   = na;

    // 1. LN1 (NCHW -> NHWC rows)
    ln1_kernel<<<MTOT, 128, 0, stream>>>(x, ln1_w, ln1_b, xn);
    // 2. conv1: (M,128)@(128,32) + gelu
    gemm_mfma<1><<<dim3(1, MTOT / BM), 256, 0, stream>>>(xn, conv1_w, conv1_b, c1, MTOT, 32, 128);
    // 3. conv2: (M,32)@(32,128)
    gemm_mfma<0><<<dim3(2, MTOT / BM), 256, 0, stream>>>(c1, conv2_w, conv2_b, t, MTOT, 128, 32);
    // 4-5. channel attention gate
    mean_partial_kernel<<<128, 128, 0, stream>>>(t, part);
    ca_kernel<<<NB, 128, 0, stream>>>(part, ca1_w, ca1_b, ca2_w, ca2_b, g2);
    // 6. qkv: (M,128)@(128,384)
    gemm_mfma<0><<<dim3(6, MTOT / BM), 256, 0, stream>>>(xn, qkv_w, qkv_b, qkv, MTOT, 384, 128);
    // 7. neighborhood attention
    na_attn_kernel<<<MTOT, 256, 0, stream>>>(qkv, rpb, na);
    // 8. proj: (M,128)@(128,128)
    gemm_mfma<0><<<dim3(2, MTOT / BM), 256, 0, stream>>>(na, proj_w, proj_b, pe, MTOT, 128, 128);
    // 9. residual + gated conv branch
    x2_kernel<<<MTOT, 128, 0, stream>>>(x, pe, t, g2, x2b);
    // 10. LN2 (rows), write into pe (proj out dead)
    ln_rows_kernel<<<MTOT, 128, 0, stream>>>(x2b, ln2_w, ln2_b, pe);
    // 11. fc1: (M,128)@(128,512) + gelu  -> hbuf (overlays xn+qkv, both dead)
    gemm_mfma<1><<<dim3(8, MTOT / BM), 256, 0, stream>>>(pe, fc1_w, fc1_b, hbuf, MTOT, 512, 128);
    // 12. fc2: (M,512)@(512,128) -> mo (overlays na, dead)
    gemm_mfma<0><<<dim3(2, MTOT / BM), 256, 0, stream>>>(hbuf, fc2_w, fc2_b, mo, MTOT, 128, 512);
    // 13. final residual + NHWC->NCHW
    final_kernel<<<MTOT, 128, 0, stream>>>(x2b, mo, out);
}

// Round 3
// 310.779 us; speedup vs baseline: 1.4684x; 1.1168x over previous
//
#include <hip/hip_runtime.h>
#include <hip/hip_bf16.h>
#include <math.h>

#define NB 4
#define CC 128
#define HH 64
#define WW 64
#define HEADS 4
#define KS 7
#define DD 32
#define HW 4096
#define MTOT 16384   // NB*HW

typedef short short8 __attribute__((ext_vector_type(8)));
typedef float floatx4 __attribute__((ext_vector_type(4)));

__device__ __forceinline__ float gelu_f(float x) {
    return 0.5f * x * (1.0f + erff(x * 0.70710678118654752440f));
}

__device__ __forceinline__ unsigned short f2bf(float f) {
    union { float f; unsigned u; } a; a.f = f;
    unsigned u = a.u;
    unsigned r = u + 0x7FFFu + ((u >> 16) & 1u);   // RNE
    return (unsigned short)(r >> 16);
}

// ---------------- block reduce (128 threads = 2 waves) ----------------
__device__ __forceinline__ float block_sum_128(float v, float* tmp) {
    #pragma unroll
    for (int off = 32; off; off >>= 1) v += __shfl_xor(v, off);
    __syncthreads();
    if ((threadIdx.x & 63) == 0) tmp[threadIdx.x >> 6] = v;
    __syncthreads();
    return tmp[0] + tmp[1];
}

// ---------------- LN1: read NCHW, write NHWC row-major (M,128) --------
__global__ __launch_bounds__(128) void ln1_kernel(
    const float* __restrict__ x, const float* __restrict__ w,
    const float* __restrict__ b, float* __restrict__ out)
{
    __shared__ float tmp[2];
    int m = blockIdx.x;            // 0..16383
    int c = threadIdx.x;
    int n = m >> 12;
    int p = m & 4095;
    float v = x[(size_t)(n * CC + c) * HW + p];
    float mu = block_sum_128(v, tmp) * (1.0f / CC);
    float d = v - mu;
    float var = block_sum_128(d * d, tmp) * (1.0f / CC);
    float r = rsqrtf(var + 1e-5f);
    out[(size_t)m * CC + c] = d * r * w[c] + b[c];
}

// ---------------- LN over contiguous rows (M,128) ---------------------
__global__ __launch_bounds__(128) void ln_rows_kernel(
    const float* __restrict__ in, const float* __restrict__ w,
    const float* __restrict__ b, float* __restrict__ out)
{
    __shared__ float tmp[2];
    int m = blockIdx.x;
    int c = threadIdx.x;
    float v = in[(size_t)m * CC + c];
    float mu = block_sum_128(v, tmp) * (1.0f / CC);
    float d = v - mu;
    float var = block_sum_128(d * d, tmp) * (1.0f / CC);
    float r = rsqrtf(var + 1e-5f);
    out[(size_t)m * CC + c] = d * r * w[c] + b[c];
}

// ---------------- bf16 MFMA GEMM: C = act(A@B + bias) -----------------
#define BM 128
#define BN 64
#define BK 32
#define LDK 40   // padded LDS row (bf16 elems); 80B stride, 16B-aligned
template<int ACT>
__global__ __launch_bounds__(256) void gemm_mfma(
    const float* __restrict__ A, const float* __restrict__ B,
    const float* __restrict__ bias, float* __restrict__ C,
    int M, int N, int K)
{
    __shared__ __align__(16) unsigned short Alds[BM][LDK];
    __shared__ __align__(16) unsigned short Blds[BN][LDK];   // transposed: [n][k]

    const int t    = threadIdx.x;
    const int w    = t >> 6;
    const int lane = t & 63;
    const int q    = lane >> 4;
    const int r16  = lane & 15;
    const int row0 = blockIdx.y * BM;
    const int col0 = blockIdx.x * BN;

    floatx4 acc[2][4] = {};

    const int ar = t >> 1;             // A row 0..127
    const int ak = (t & 1) * 16;       // A k offset {0,16}
    const int bk = t >> 3;             // B k row 0..31
    const int bn = (t & 7) * 8;        // B n offset 0..56

    for (int k0 = 0; k0 < K; k0 += BK) {
        {
            const float* src = A + (size_t)(row0 + ar) * K + k0 + ak;
            float4 v0 = *(const float4*)(src);
            float4 v1 = *(const float4*)(src + 4);
            float4 v2 = *(const float4*)(src + 8);
            float4 v3 = *(const float4*)(src + 12);
            short8 s0, s1;
            s0[0] = f2bf(v0.x); s0[1] = f2bf(v0.y); s0[2] = f2bf(v0.z); s0[3] = f2bf(v0.w);
            s0[4] = f2bf(v1.x); s0[5] = f2bf(v1.y); s0[6] = f2bf(v1.z); s0[7] = f2bf(v1.w);
            s1[0] = f2bf(v2.x); s1[1] = f2bf(v2.y); s1[2] = f2bf(v2.z); s1[3] = f2bf(v2.w);
            s1[4] = f2bf(v3.x); s1[5] = f2bf(v3.y); s1[6] = f2bf(v3.z); s1[7] = f2bf(v3.w);
            *(short8*)(&Alds[ar][ak])     = s0;
            *(short8*)(&Alds[ar][ak + 8]) = s1;
        }
        {
            const float* src = B + (size_t)(k0 + bk) * N + col0 + bn;
            if (col0 + bn + 8 <= N) {
                float4 b0 = *(const float4*)(src);
                float4 b1 = *(const float4*)(src + 4);
                Blds[bn + 0][bk] = f2bf(b0.x); Blds[bn + 1][bk] = f2bf(b0.y);
                Blds[bn + 2][bk] = f2bf(b0.z); Blds[bn + 3][bk] = f2bf(b0.w);
                Blds[bn + 4][bk] = f2bf(b1.x); Blds[bn + 5][bk] = f2bf(b1.y);
                Blds[bn + 6][bk] = f2bf(b1.z); Blds[bn + 7][bk] = f2bf(b1.w);
            } else {
                #pragma unroll
                for (int u = 0; u < 8; u++) {
                    int col = col0 + bn + u;
                    Blds[bn + u][bk] = (col < N) ? f2bf(src[u]) : (unsigned short)0;
                }
            }
        }
        __syncthreads();

        short8 af[2], bfm[4];
        #pragma unroll
        for (int mt = 0; mt < 2; mt++)
            af[mt] = *(const short8*)(&Alds[w * 32 + mt * 16 + r16][q * 8]);
        #pragma unroll
        for (int nt = 0; nt < 4; nt++)
            bfm[nt] = *(const short8*)(&Blds[nt * 16 + r16][q * 8]);

        #pragma unroll
        for (int mt = 0; mt < 2; mt++)
            #pragma unroll
            for (int nt = 0; nt < 4; nt++)
                acc[mt][nt] = __builtin_amdgcn_mfma_f32_16x16x32_bf16(
                    af[mt], bfm[nt], acc[mt][nt], 0, 0, 0);
        __syncthreads();
    }

    #pragma unroll
    for (int mt = 0; mt < 2; mt++) {
        #pragma unroll
        for (int nt = 0; nt < 4; nt++) {
            int col = col0 + nt * 16 + r16;
            if (col < N) {
                float bv = bias[col];
                #pragma unroll
                for (int reg = 0; reg < 4; reg++) {
                    int row = row0 + w * 32 + mt * 16 + q * 4 + reg;
                    float v = acc[mt][nt][reg] + bv;
                    if (ACT == 1) v = gelu_f(v);
                    C[(size_t)row * N + col] = v;
                }
            }
        }
    }
}

// ---------------- HW-mean partials: t (M,128) -> part (4*32,128) ------
__global__ __launch_bounds__(128) void mean_partial_kernel(
    const float* __restrict__ t, float* __restrict__ part)
{
    int blk = blockIdx.x;          // 0..127 = n*32 + chunk
    int n = blk >> 5;
    int chunk = blk & 31;
    int c = threadIdx.x;
    float s = 0.f;
    int base = n * HW + chunk * 128;
    for (int r = 0; r < 128; r++)
        s += t[(size_t)(base + r) * CC + c];
    part[(size_t)blk * CC + c] = s;
}

// ---------------- channel-attention tiny MLP --------------------------
__global__ __launch_bounds__(128) void ca_kernel(
    const float* __restrict__ part,
    const float* __restrict__ ca1_w, const float* __restrict__ ca1_b,
    const float* __restrict__ ca2_w, const float* __restrict__ ca2_b,
    float* __restrict__ g2)
{
    __shared__ float gs[128];
    __shared__ float h1[7];
    int n = blockIdx.x;
    int c = threadIdx.x;
    float s = 0.f;
    for (int k = 0; k < 32; k++) s += part[(size_t)(n * 32 + k) * CC + c];
    float gm = s * (1.0f / HW);
    gs[c] = gm;
    __syncthreads();
    if (c < 7) {
        float a = ca1_b[c];
        for (int k = 0; k < 128; k++) a += gs[k] * ca1_w[k * 7 + c];
        h1[c] = fmaxf(a, 0.f);
    }
    __syncthreads();
    float o = ca2_b[c];
    #pragma unroll
    for (int r = 0; r < 7; r++) o += h1[r] * ca2_w[r * 128 + c];
    g2[(size_t)n * CC + c] = 1.0f / (1.0f + expf(-o));
}

// ---------------- tiled neighborhood attention ------------------------
// block = 8x8 query tile x 1 head; 256 threads = 4 waves, 16 queries/wave.
// Window (<=14x14) K/V + Q + rpb staged in LDS; score/softmax/PV from LDS.
// Kb transposed [d][key] (lane=key reads conflict-free); Vb [key][d]
// (lane=d reads conflict-free). blockIdx: head fastest -> same-tile heads
// adjacent -> window L2 reuse.
__global__ __launch_bounds__(256) void na_tile_kernel(
    const float* __restrict__ qkv, const float* __restrict__ rpb,
    float* __restrict__ out)
{
    __shared__ float Kb[DD][200];        // [d][key], key stride 200 (pad)
    __shared__ float Vb[196][DD];        // [key][d]
    __shared__ float Qb[64][DD];         // pre-scaled
    __shared__ float rb[169];            // rpb for this head
    __shared__ float sp[4][64];          // per-wave softmax probs

    const int b    = blockIdx.x;
    const int h    = b & 3;
    const int tile = b >> 2;
    const int n    = tile >> 6;
    const int ti   = (tile >> 3) & 7;
    const int tj   = tile & 7;
    const int t    = threadIdx.x;
    const int w    = t >> 6;
    const int lane = t & 63;

    const int i0 = ti * 8, j0 = tj * 8;
    const int wi0 = max(i0 - 3, 0);
    const int wj0 = max(j0 - 3, 0);
    const int R  = min(wi0 + 13, HH - 1) - wi0 + 1;   // rows loaded
    const int Rj = min(wj0 + 13, WW - 1) - wj0 + 1;   // cols loaded

    // ---- stage K,V window: 196 pixels x 16 float4 chunks (K:8, V:8) ----
    for (int idx = t; idx < 196 * 16; idx += 256) {
        int pixel = idx >> 4;
        int ch    = idx & 15;
        int pr = pixel / 14, pc = pixel % 14;
        if (pr < R && pc < Rj) {
            int seg = ch >> 3;          // 0=K, 1=V
            int c4  = ch & 7;           // which float4 of 32 floats
            const float* src = qkv
                + ((size_t)((n * HH + wi0 + pr) * WW + wj0 + pc)) * 384
                + 128 + seg * 128 + h * DD + c4 * 4;
            float4 v = *(const float4*)src;
            if (seg == 0) {
                int d0 = c4 * 4;
                Kb[d0 + 0][pixel] = v.x; Kb[d0 + 1][pixel] = v.y;
                Kb[d0 + 2][pixel] = v.z; Kb[d0 + 3][pixel] = v.w;
            } else {
                *(float4*)&Vb[pixel][c4 * 4] = v;
            }
        }
    }
    // ---- stage Q (scaled): 64 q x 8 float4 ----
    for (int idx = t; idx < 64 * 8; idx += 256) {
        int q  = idx >> 3;
        int c4 = idx & 7;
        int qi = q >> 3, qj = q & 7;
        size_t m = (size_t)((n * HH + i0 + qi) * WW + j0 + qj);
        float4 v = *(const float4*)(qkv + m * 384 + h * DD + c4 * 4);
        const float sc = 0.17677669529663688110f;   // 32^-0.5
        v.x *= sc; v.y *= sc; v.z *= sc; v.w *= sc;
        *(float4*)&Qb[q][c4 * 4] = v;
    }
    // ---- stage rpb ----
    if (t < 169) rb[t] = rpb[h * 169 + t];
    __syncthreads();

    // ---- compute: wave w handles queries w*16 .. w*16+15 ----
    for (int qq = 0; qq < 16; qq++) {
        int q  = w * 16 + qq;
        int qi = q >> 3, qj = q & 7;
        int i = i0 + qi, j = j0 + qj;
        int ni = min(max(i - 3, 0), HH - KS);
        int nj = min(max(j - 3, 0), WW - KS);
        int keybase = (ni - wi0) * 14 + (nj - wj0);

        // preload q into regs (broadcast reads)
        float4 qv[8];
        #pragma unroll
        for (int u = 0; u < 8; u++) qv[u] = *(const float4*)&Qb[q][u * 4];

        int aa = min(lane, KS * KS - 1);
        int ar = aa / KS, ac = aa % KS;
        int key = keybase + ar * 14 + ac;
        float s = 0.f;
        #pragma unroll
        for (int u = 0; u < 8; u++) {
            s += qv[u].x * Kb[u * 4 + 0][key];
            s += qv[u].y * Kb[u * 4 + 1][key];
            s += qv[u].z * Kb[u * 4 + 2][key];
            s += qv[u].w * Kb[u * 4 + 3][key];
        }
        // bias: bi = ni - i + 6 + ar, bj = nj - j + 6 + ac
        s += rb[(ni - i + 6 + ar) * 13 + (nj - j + 6 + ac)];
        float score = (lane < KS * KS) ? s : -INFINITY;

        float mx = score;
        #pragma unroll
        for (int off = 32; off; off >>= 1) mx = fmaxf(mx, __shfl_xor(mx, off));
        float e = (lane < KS * KS) ? __expf(score - mx) : 0.f;
        float sm = e;
        #pragma unroll
        for (int off = 32; off; off >>= 1) sm += __shfl_xor(sm, off);
        sp[w][lane] = e / sm;          // same-wave write->read, no barrier

        // ---- PV: half-wave splits keys; lane = (half, d) ----
        int half = lane >> 5, d = lane & 31;
        float acc = 0.f;
        int rr = 0, cc = half;         // a2 = half; step 2 over 49 keys
        #pragma unroll
        for (int it = 0; it < 25; it++) {
            int a2 = 2 * it + half;
            if (a2 < 49) {
                acc += sp[w][a2] * Vb[keybase + rr * 14 + cc][d];
            }
            cc += 2;
            if (cc >= KS) { cc -= KS; rr++; }
        }
        acc += __shfl_xor(acc, 32);
        if (lane < 32) {
            size_t m = (size_t)((n * HH + i) * WW + j);
            out[m * CC + h * DD + d] = acc;
        }
    }
}

// ---------------- x2 = shortcut + proj_out + 0.02 * t * g -------------
__global__ __launch_bounds__(128) void x2_kernel(
    const float* __restrict__ x, const float* __restrict__ projout,
    const float* __restrict__ t, const float* __restrict__ g2,
    float* __restrict__ x2)
{
    int m = blockIdx.x;
    int c = threadIdx.x;
    int n = m >> 12;
    int p = m & 4095;
    float sc = x[(size_t)(n * CC + c) * HW + p];
    size_t idx = (size_t)m * CC + c;
    x2[idx] = sc + projout[idx] + 0.02f * t[idx] * g2[(size_t)n * CC + c];
}

// ---------------- out NCHW = x2 + m -----------------------------------
__global__ __launch_bounds__(128) void final_kernel(
    const float* __restrict__ x2, const float* __restrict__ mo,
    float* __restrict__ out)
{
    int m = blockIdx.x;
    int c = threadIdx.x;
    int n = m >> 12;
    int p = m & 4095;
    size_t idx = (size_t)m * CC + c;
    out[(size_t)(n * CC + c) * HW + p] = x2[idx] + mo[idx];
}

extern "C" void kernel_launch(void* const* d_in, const int* in_sizes, int n_in,
                              void* d_out, int out_size, void* d_ws, size_t ws_size,
                              hipStream_t stream)
{
    const float* x       = (const float*)d_in[0];
    const float* ln1_w   = (const float*)d_in[1];
    const float* ln1_b   = (const float*)d_in[2];
    const float* ln2_w   = (const float*)d_in[3];
    const float* ln2_b   = (const float*)d_in[4];
    const float* qkv_w   = (const float*)d_in[5];
    const float* qkv_b   = (const float*)d_in[6];
    const float* proj_w  = (const float*)d_in[7];
    const float* proj_b  = (const float*)d_in[8];
    const float* rpb     = (const float*)d_in[9];
    const float* conv1_w = (const float*)d_in[10];
    const float* conv1_b = (const float*)d_in[11];
    const float* conv2_w = (const float*)d_in[12];
    const float* conv2_b = (const float*)d_in[13];
    const float* ca1_w   = (const float*)d_in[14];
    const float* ca1_b   = (const float*)d_in[15];
    const float* ca2_w   = (const float*)d_in[16];
    const float* ca2_b   = (const float*)d_in[17];
    const float* fc1_w   = (const float*)d_in[18];
    const float* fc1_b   = (const float*)d_in[19];
    const float* fc2_w   = (const float*)d_in[20];
    const float* fc2_b   = (const float*)d_in[21];
    float* out = (float*)d_out;

    // workspace layout (floats). hbuf (M*512) overlays xn+qkv (dead by fc1).
    float* f0   = (float*)d_ws;
    float* xn   = f0;                       // M*128 = 2,097,152
    float* qkv  = f0 + 2097152;             // M*384 = 6,291,456
    float* hbuf = f0;                       // M*512 = 8,388,608 (overlay)
    float* t    = f0 + 8388608;             // M*128
    float* na   = f0 + 10485760;            // M*128  (later: fc2 out)
    float* pe   = f0 + 12582912;            // M*128  (proj out, later ln2 out)
    float* x2b  = f0 + 14680064;            // M*128
    float* part = f0 + 16777216;            // 128*128 = 16,384
    float* g2   = f0 + 16793600;            // 512
    float* c1   = f0 + 16794112;            // M*32 = 524,288
    float* mo   = na;

    // 1. LN1 (NCHW -> NHWC rows)
    ln1_kernel<<<MTOT, 128, 0, stream>>>(x, ln1_w, ln1_b, xn);
    // 2. conv1: (M,128)@(128,32) + gelu
    gemm_mfma<1><<<dim3(1, MTOT / BM), 256, 0, stream>>>(xn, conv1_w, conv1_b, c1, MTOT, 32, 128);
    // 3. conv2: (M,32)@(32,128)
    gemm_mfma<0><<<dim3(2, MTOT / BM), 256, 0, stream>>>(c1, conv2_w, conv2_b, t, MTOT, 128, 32);
    // 4-5. channel attention gate
    mean_partial_kernel<<<128, 128, 0, stream>>>(t, part);
    ca_kernel<<<NB, 128, 0, stream>>>(part, ca1_w, ca1_b, ca2_w, ca2_b, g2);
    // 6. qkv: (M,128)@(128,384)
    gemm_mfma<0><<<dim3(6, MTOT / BM), 256, 0, stream>>>(xn, qkv_w, qkv_b, qkv, MTOT, 384, 128);
    // 7. tiled neighborhood attention (8x8 tile x head)
    na_tile_kernel<<<1024, 256, 0, stream>>>(qkv, rpb, na);
    // 8. proj: (M,128)@(128,128)
    gemm_mfma<0><<<dim3(2, MTOT / BM), 256, 0, stream>>>(na, proj_w, proj_b, pe, MTOT, 128, 128);
    // 9. residual + gated conv branch
    x2_kernel<<<MTOT, 128, 0, stream>>>(x, pe, t, g2, x2b);
    // 10. LN2 (rows), write into pe (proj out dead)
    ln_rows_kernel<<<MTOT, 128, 0, stream>>>(x2b, ln2_w, ln2_b, pe);
    // 11. fc1: (M,128)@(128,512) + gelu  -> hbuf (overlays xn+qkv, both dead)
    gemm_mfma<1><<<dim3(8, MTOT / BM), 256, 0, stream>>>(pe, fc1_w, fc1_b, hbuf, MTOT, 512, 128);
    // 12. fc2: (M,512)@(512,128) -> mo (overlays na, dead)
    gemm_mfma<0><<<dim3(2, MTOT / BM), 256, 0, stream>>>(hbuf, fc2_w, fc2_b, mo, MTOT, 128, 512);
    // 13. final residual + NHWC->NCHW
    final_kernel<<<MTOT, 128, 0, stream>>>(x2b, mo, out);
}

// Round 4
// 291.219 us; speedup vs baseline: 1.5671x; 1.0672x over previous
//
#include <hip/hip_runtime.h>
#include <hip/hip_bf16.h>
#include <math.h>

#define NB 4
#define CC 128
#define HH 64
#define WW 64
#define HEADS 4
#define KS 7
#define DD 32
#define HW 4096
#define MTOT 16384   // NB*HW

typedef short short8 __attribute__((ext_vector_type(8)));
typedef float floatx4 __attribute__((ext_vector_type(4)));
typedef unsigned short ushort4v __attribute__((ext_vector_type(4)));

__device__ __forceinline__ float gelu_f(float x) {
    return 0.5f * x * (1.0f + erff(x * 0.70710678118654752440f));
}

__device__ __forceinline__ unsigned short f2bf(float f) {
    union { float f; unsigned u; } a; a.f = f;
    unsigned u = a.u;
    unsigned r = u + 0x7FFFu + ((u >> 16) & 1u);   // RNE
    return (unsigned short)(r >> 16);
}

__device__ __forceinline__ float bflo(unsigned p) { return __uint_as_float(p << 16); }
__device__ __forceinline__ float bfhi(unsigned p) { return __uint_as_float(p & 0xffff0000u); }

// ---------------- block reduce (128 threads = 2 waves) ----------------
__device__ __forceinline__ float block_sum_128(float v, float* tmp) {
    #pragma unroll
    for (int off = 32; off; off >>= 1) v += __shfl_xor(v, off);
    __syncthreads();
    if ((threadIdx.x & 63) == 0) tmp[threadIdx.x >> 6] = v;
    __syncthreads();
    return tmp[0] + tmp[1];
}

// ---------------- LN1: read NCHW, write NHWC row-major (M,128) --------
__global__ __launch_bounds__(128) void ln1_kernel(
    const float* __restrict__ x, const float* __restrict__ w,
    const float* __restrict__ b, float* __restrict__ out)
{
    __shared__ float tmp[2];
    int m = blockIdx.x;
    int c = threadIdx.x;
    int n = m >> 12;
    int p = m & 4095;
    float v = x[(size_t)(n * CC + c) * HW + p];
    float mu = block_sum_128(v, tmp) * (1.0f / CC);
    float d = v - mu;
    float var = block_sum_128(d * d, tmp) * (1.0f / CC);
    float r = rsqrtf(var + 1e-5f);
    out[(size_t)m * CC + c] = d * r * w[c] + b[c];
}

// ---------------- LN over contiguous rows (M,128) ---------------------
__global__ __launch_bounds__(128) void ln_rows_kernel(
    const float* __restrict__ in, const float* __restrict__ w,
    const float* __restrict__ b, float* __restrict__ out)
{
    __shared__ float tmp[2];
    int m = blockIdx.x;
    int c = threadIdx.x;
    float v = in[(size_t)m * CC + c];
    float mu = block_sum_128(v, tmp) * (1.0f / CC);
    float d = v - mu;
    float var = block_sum_128(d * d, tmp) * (1.0f / CC);
    float r = rsqrtf(var + 1e-5f);
    out[(size_t)m * CC + c] = d * r * w[c] + b[c];
}

// ---------------- bf16 MFMA GEMM, BM=128/BN=64 ------------------------
#define BM 128
#define BN 64
#define BK 32
#define LDK 40   // padded LDS row (bf16 elems)
template<int ACT>
__global__ __launch_bounds__(256) void gemm_mfma(
    const float* __restrict__ A, const float* __restrict__ B,
    const float* __restrict__ bias, float* __restrict__ C,
    int M, int N, int K)
{
    __shared__ __align__(16) unsigned short Alds[BM][LDK];
    __shared__ __align__(16) unsigned short Blds[BN][LDK];   // [n][k]

    const int t    = threadIdx.x;
    const int w    = t >> 6;
    const int lane = t & 63;
    const int q    = lane >> 4;
    const int r16  = lane & 15;
    const int row0 = blockIdx.y * BM;
    const int col0 = blockIdx.x * BN;

    floatx4 acc[2][4] = {};

    const int ar = t >> 1;
    const int ak = (t & 1) * 16;
    const int bk = t >> 3;
    const int bn = (t & 7) * 8;

    for (int k0 = 0; k0 < K; k0 += BK) {
        {
            const float* src = A + (size_t)(row0 + ar) * K + k0 + ak;
            float4 v0 = *(const float4*)(src);
            float4 v1 = *(const float4*)(src + 4);
            float4 v2 = *(const float4*)(src + 8);
            float4 v3 = *(const float4*)(src + 12);
            short8 s0, s1;
            s0[0] = f2bf(v0.x); s0[1] = f2bf(v0.y); s0[2] = f2bf(v0.z); s0[3] = f2bf(v0.w);
            s0[4] = f2bf(v1.x); s0[5] = f2bf(v1.y); s0[6] = f2bf(v1.z); s0[7] = f2bf(v1.w);
            s1[0] = f2bf(v2.x); s1[1] = f2bf(v2.y); s1[2] = f2bf(v2.z); s1[3] = f2bf(v2.w);
            s1[4] = f2bf(v3.x); s1[5] = f2bf(v3.y); s1[6] = f2bf(v3.z); s1[7] = f2bf(v3.w);
            *(short8*)(&Alds[ar][ak])     = s0;
            *(short8*)(&Alds[ar][ak + 8]) = s1;
        }
        {
            const float* src = B + (size_t)(k0 + bk) * N + col0 + bn;
            if (col0 + bn + 8 <= N) {
                float4 b0 = *(const float4*)(src);
                float4 b1 = *(const float4*)(src + 4);
                Blds[bn + 0][bk] = f2bf(b0.x); Blds[bn + 1][bk] = f2bf(b0.y);
                Blds[bn + 2][bk] = f2bf(b0.z); Blds[bn + 3][bk] = f2bf(b0.w);
                Blds[bn + 4][bk] = f2bf(b1.x); Blds[bn + 5][bk] = f2bf(b1.y);
                Blds[bn + 6][bk] = f2bf(b1.z); Blds[bn + 7][bk] = f2bf(b1.w);
            } else {
                #pragma unroll
                for (int u = 0; u < 8; u++) {
                    int col = col0 + bn + u;
                    Blds[bn + u][bk] = (col < N) ? f2bf(src[u]) : (unsigned short)0;
                }
            }
        }
        __syncthreads();

        short8 af[2], bfm[4];
        #pragma unroll
        for (int mt = 0; mt < 2; mt++)
            af[mt] = *(const short8*)(&Alds[w * 32 + mt * 16 + r16][q * 8]);
        #pragma unroll
        for (int nt = 0; nt < 4; nt++)
            bfm[nt] = *(const short8*)(&Blds[nt * 16 + r16][q * 8]);

        #pragma unroll
        for (int mt = 0; mt < 2; mt++)
            #pragma unroll
            for (int nt = 0; nt < 4; nt++)
                acc[mt][nt] = __builtin_amdgcn_mfma_f32_16x16x32_bf16(
                    af[mt], bfm[nt], acc[mt][nt], 0, 0, 0);
        __syncthreads();
    }

    #pragma unroll
    for (int mt = 0; mt < 2; mt++) {
        #pragma unroll
        for (int nt = 0; nt < 4; nt++) {
            int col = col0 + nt * 16 + r16;
            if (col < N) {
                float bv = bias[col];
                #pragma unroll
                for (int reg = 0; reg < 4; reg++) {
                    int row = row0 + w * 32 + mt * 16 + q * 4 + reg;
                    float v = acc[mt][nt][reg] + bv;
                    if (ACT == 1) v = gelu_f(v);
                    C[(size_t)row * N + col] = v;
                }
            }
        }
    }
}

// ---------------- bf16 MFMA GEMM, BM=64/BN=64 (small-N, more blocks) --
template<int ACT>
__global__ __launch_bounds__(256) void gemm_mfma64(
    const float* __restrict__ A, const float* __restrict__ B,
    const float* __restrict__ bias, float* __restrict__ C,
    int M, int N, int K)
{
    __shared__ __align__(16) unsigned short Alds[64][LDK];
    __shared__ __align__(16) unsigned short Blds[64][LDK];

    const int t    = threadIdx.x;
    const int w    = t >> 6;
    const int lane = t & 63;
    const int q    = lane >> 4;
    const int r16  = lane & 15;
    const int row0 = blockIdx.y * 64;
    const int col0 = blockIdx.x * 64;

    floatx4 acc[4] = {};

    const int ar = t >> 2;            // 0..63
    const int ak = (t & 3) * 8;       // 0,8,16,24
    const int bk = t >> 3;
    const int bn = (t & 7) * 8;

    for (int k0 = 0; k0 < K; k0 += BK) {
        {
            const float* src = A + (size_t)(row0 + ar) * K + k0 + ak;
            float4 v0 = *(const float4*)(src);
            float4 v1 = *(const float4*)(src + 4);
            short8 s0;
            s0[0] = f2bf(v0.x); s0[1] = f2bf(v0.y); s0[2] = f2bf(v0.z); s0[3] = f2bf(v0.w);
            s0[4] = f2bf(v1.x); s0[5] = f2bf(v1.y); s0[6] = f2bf(v1.z); s0[7] = f2bf(v1.w);
            *(short8*)(&Alds[ar][ak]) = s0;
        }
        {
            const float* src = B + (size_t)(k0 + bk) * N + col0 + bn;
            if (col0 + bn + 8 <= N) {
                float4 b0 = *(const float4*)(src);
                float4 b1 = *(const float4*)(src + 4);
                Blds[bn + 0][bk] = f2bf(b0.x); Blds[bn + 1][bk] = f2bf(b0.y);
                Blds[bn + 2][bk] = f2bf(b0.z); Blds[bn + 3][bk] = f2bf(b0.w);
                Blds[bn + 4][bk] = f2bf(b1.x); Blds[bn + 5][bk] = f2bf(b1.y);
                Blds[bn + 6][bk] = f2bf(b1.z); Blds[bn + 7][bk] = f2bf(b1.w);
            } else {
                #pragma unroll
                for (int u = 0; u < 8; u++) {
                    int col = col0 + bn + u;
                    Blds[bn + u][bk] = (col < N) ? f2bf(src[u]) : (unsigned short)0;
                }
            }
        }
        __syncthreads();

        short8 af = *(const short8*)(&Alds[w * 16 + r16][q * 8]);
        short8 bfm[4];
        #pragma unroll
        for (int nt = 0; nt < 4; nt++)
            bfm[nt] = *(const short8*)(&Blds[nt * 16 + r16][q * 8]);
        #pragma unroll
        for (int nt = 0; nt < 4; nt++)
            acc[nt] = __builtin_amdgcn_mfma_f32_16x16x32_bf16(af, bfm[nt], acc[nt], 0, 0, 0);
        __syncthreads();
    }

    #pragma unroll
    for (int nt = 0; nt < 4; nt++) {
        int col = col0 + nt * 16 + r16;
        if (col < N) {
            float bv = bias[col];
            #pragma unroll
            for (int reg = 0; reg < 4; reg++) {
                int row = row0 + w * 16 + q * 4 + reg;
                float v = acc[nt][reg] + bv;
                if (ACT == 1) v = gelu_f(v);
                C[(size_t)row * N + col] = v;
            }
        }
    }
}

// ---------------- HW-mean partials ------------------------------------
__global__ __launch_bounds__(128) void mean_partial_kernel(
    const float* __restrict__ t, float* __restrict__ part)
{
    int blk = blockIdx.x;
    int n = blk >> 5;
    int chunk = blk & 31;
    int c = threadIdx.x;
    float s = 0.f;
    int base = n * HW + chunk * 128;
    for (int r = 0; r < 128; r++)
        s += t[(size_t)(base + r) * CC + c];
    part[(size_t)blk * CC + c] = s;
}

// ---------------- channel-attention tiny MLP --------------------------
__global__ __launch_bounds__(128) void ca_kernel(
    const float* __restrict__ part,
    const float* __restrict__ ca1_w, const float* __restrict__ ca1_b,
    const float* __restrict__ ca2_w, const float* __restrict__ ca2_b,
    float* __restrict__ g2)
{
    __shared__ float gs[128];
    __shared__ float h1[7];
    int n = blockIdx.x;
    int c = threadIdx.x;
    float s = 0.f;
    for (int k = 0; k < 32; k++) s += part[(size_t)(n * 32 + k) * CC + c];
    float gm = s * (1.0f / HW);
    gs[c] = gm;
    __syncthreads();
    if (c < 7) {
        float a = ca1_b[c];
        for (int k = 0; k < 128; k++) a += gs[k] * ca1_w[k * 7 + c];
        h1[c] = fmaxf(a, 0.f);
    }
    __syncthreads();
    float o = ca2_b[c];
    #pragma unroll
    for (int r = 0; r < 7; r++) o += h1[r] * ca2_w[r * 128 + c];
    g2[(size_t)n * CC + c] = 1.0f / (1.0f + expf(-o));
}

// ---------------- tiled neighborhood attention (bf16 LDS) -------------
// block = 8x8 query tile x 1 head; 256 threads = 4 waves, 16 q/wave.
// K: Kb32[dpair][key] (stride 210 dwords: 420 % 32 = 4 -> staging writes
// of one pixel's 8 chunks land on 8 distinct bank groups). V: [key][dpair].
// All bf16-pair packed; ~32 KB LDS -> 4-5 blocks/CU.
__global__ __launch_bounds__(256) void na_tile_kernel(
    const float* __restrict__ qkv, const float* __restrict__ rpb,
    float* __restrict__ out)
{
    __shared__ unsigned Kb32[16][210];       // 13440 B
    __shared__ unsigned Vb32[196][16];       // 12544 B
    __shared__ unsigned short Qb[64][32];    // 4096 B, pre-scaled bf16
    __shared__ float rb[169];
    __shared__ float sp[4][64];

    const int b    = blockIdx.x;
    const int h    = b & 3;
    const int tile = b >> 2;
    const int n    = tile >> 6;
    const int ti   = (tile >> 3) & 7;
    const int tj   = tile & 7;
    const int t    = threadIdx.x;
    const int w    = t >> 6;
    const int lane = t & 63;

    const int i0 = ti * 8, j0 = tj * 8;
    const int wi0 = max(i0 - 3, 0);
    const int wj0 = max(j0 - 3, 0);
    const int R  = min(wi0 + 13, HH - 1) - wi0 + 1;
    const int Rj = min(wj0 + 13, WW - 1) - wj0 + 1;

    // ---- stage K,V window ----
    for (int idx = t; idx < 196 * 16; idx += 256) {
        int pixel = idx >> 4, ch = idx & 15;
        int pr = pixel / 14, pc = pixel % 14;
        if (pr < R && pc < Rj) {
            int seg = ch >> 3, c4 = ch & 7;
            const float* src = qkv
                + ((size_t)((n * HH + wi0 + pr) * WW + wj0 + pc)) * 384
                + 128 + seg * 128 + h * DD + c4 * 4;
            float4 v = *(const float4*)src;
            unsigned lo = ((unsigned)f2bf(v.x)) | (((unsigned)f2bf(v.y)) << 16);
            unsigned hi = ((unsigned)f2bf(v.z)) | (((unsigned)f2bf(v.w)) << 16);
            if (seg == 0) {
                Kb32[2 * c4][pixel]     = lo;
                Kb32[2 * c4 + 1][pixel] = hi;
            } else {
                Vb32[pixel][2 * c4]     = lo;
                Vb32[pixel][2 * c4 + 1] = hi;
            }
        }
    }
    // ---- stage Q (scaled, bf16) ----
    for (int idx = t; idx < 64 * 8; idx += 256) {
        int q = idx >> 3, c4 = idx & 7;
        int qi = q >> 3, qj = q & 7;
        size_t m = (size_t)((n * HH + i0 + qi) * WW + j0 + qj);
        float4 v = *(const float4*)(qkv + m * 384 + h * DD + c4 * 4);
        const float sc = 0.17677669529663688110f;   // 32^-0.5
        ushort4v s;
        s.x = f2bf(v.x * sc); s.y = f2bf(v.y * sc);
        s.z = f2bf(v.z * sc); s.w = f2bf(v.w * sc);
        *(ushort4v*)&Qb[q][c4 * 4] = s;
    }
    if (t < 169) rb[t] = rpb[h * 169 + t];
    __syncthreads();

    for (int qq = 0; qq < 16; qq++) {
        int q  = w * 16 + qq;
        int qi = q >> 3, qj = q & 7;
        int i = i0 + qi, j = j0 + qj;
        int ni = min(max(i - 3, 0), HH - KS);
        int nj = min(max(j - 3, 0), WW - KS);
        int keybase = (ni - wi0) * 14 + (nj - wj0);

        unsigned qp[16];
        const unsigned* Qbu = (const unsigned*)&Qb[q][0];
        #pragma unroll
        for (int u = 0; u < 16; u++) qp[u] = Qbu[u];    // broadcast reads

        int aa = min(lane, KS * KS - 1);
        int ar = aa / KS, ac = aa % KS;
        int key = keybase + ar * 14 + ac;
        float s = 0.f;
        #pragma unroll
        for (int dp = 0; dp < 16; dp++) {
            unsigned kv = Kb32[dp][key];
            s += bflo(qp[dp]) * bflo(kv);
            s += bfhi(qp[dp]) * bfhi(kv);
        }
        s += rb[(ni - i + 6 + ar) * 13 + (nj - j + 6 + ac)];
        float score = (lane < KS * KS) ? s : -INFINITY;

        float mx = score;
        #pragma unroll
        for (int off = 32; off; off >>= 1) mx = fmaxf(mx, __shfl_xor(mx, off));
        float e = (lane < KS * KS) ? __expf(score - mx) : 0.f;
        float sm = e;
        #pragma unroll
        for (int off = 32; off; off >>= 1) sm += __shfl_xor(sm, off);
        sp[w][lane] = e / sm;          // same-wave write->read

        // ---- PV: lane = (quarter, dpair); key stride 4 ----
        int quarter = lane >> 4, dpv = lane & 15;
        float accl = 0.f, acch = 0.f;
        int rr = 0, cc = quarter;
        #pragma unroll
        for (int it = 0; it < 13; it++) {
            int a4 = 4 * it + quarter;
            if (a4 < 49) {
                float p = sp[w][a4];
                unsigned pv = Vb32[keybase + rr * 14 + cc][dpv];
                accl += p * bflo(pv);
                acch += p * bfhi(pv);
            }
            cc += 4; if (cc >= KS) { cc -= KS; rr++; }
        }
        accl += __shfl_xor(accl, 16); accl += __shfl_xor(accl, 32);
        acch += __shfl_xor(acch, 16); acch += __shfl_xor(acch, 32);
        if (lane < 16) {
            size_t m = (size_t)((n * HH + i) * WW + j);
            *(float2*)(out + m * CC + h * DD + 2 * dpv) = make_float2(accl, acch);
        }
    }
}

// ---------------- x2 = shortcut + proj_out + 0.02 * t * g -------------
__global__ __launch_bounds__(128) void x2_kernel(
    const float* __restrict__ x, const float* __restrict__ projout,
    const float* __restrict__ t, const float* __restrict__ g2,
    float* __restrict__ x2)
{
    int m = blockIdx.x;
    int c = threadIdx.x;
    int n = m >> 12;
    int p = m & 4095;
    float sc = x[(size_t)(n * CC + c) * HW + p];
    size_t idx = (size_t)m * CC + c;
    x2[idx] = sc + projout[idx] + 0.02f * t[idx] * g2[(size_t)n * CC + c];
}

// ---------------- out NCHW = x2 + m -----------------------------------
__global__ __launch_bounds__(128) void final_kernel(
    const float* __restrict__ x2, const float* __restrict__ mo,
    float* __restrict__ out)
{
    int m = blockIdx.x;
    int c = threadIdx.x;
    int n = m >> 12;
    int p = m & 4095;
    size_t idx = (size_t)m * CC + c;
    out[(size_t)(n * CC + c) * HW + p] = x2[idx] + mo[idx];
}

extern "C" void kernel_launch(void* const* d_in, const int* in_sizes, int n_in,
                              void* d_out, int out_size, void* d_ws, size_t ws_size,
                              hipStream_t stream)
{
    const float* x       = (const float*)d_in[0];
    const float* ln1_w   = (const float*)d_in[1];
    const float* ln1_b   = (const float*)d_in[2];
    const float* ln2_w   = (const float*)d_in[3];
    const float* ln2_b   = (const float*)d_in[4];
    const float* qkv_w   = (const float*)d_in[5];
    const float* qkv_b   = (const float*)d_in[6];
    const float* proj_w  = (const float*)d_in[7];
    const float* proj_b  = (const float*)d_in[8];
    const float* rpb     = (const float*)d_in[9];
    const float* conv1_w = (const float*)d_in[10];
    const float* conv1_b = (const float*)d_in[11];
    const float* conv2_w = (const float*)d_in[12];
    const float* conv2_b = (const float*)d_in[13];
    const float* ca1_w   = (const float*)d_in[14];
    const float* ca1_b   = (const float*)d_in[15];
    const float* ca2_w   = (const float*)d_in[16];
    const float* ca2_b   = (const float*)d_in[17];
    const float* fc1_w   = (const float*)d_in[18];
    const float* fc1_b   = (const float*)d_in[19];
    const float* fc2_w   = (const float*)d_in[20];
    const float* fc2_b   = (const float*)d_in[21];
    float* out = (float*)d_out;

    float* f0   = (float*)d_ws;
    float* xn   = f0;                       // M*128
    float* qkv  = f0 + 2097152;             // M*384
    float* hbuf = f0;                       // M*512 (overlay, fc1 out)
    float* t    = f0 + 8388608;             // M*128
    float* na   = f0 + 10485760;            // M*128 (later fc2 out)
    float* pe   = f0 + 12582912;            // M*128 (proj out / ln2 out)
    float* x2b  = f0 + 14680064;            // M*128
    float* part = f0 + 16777216;            // 128*128
    float* g2   = f0 + 16793600;            // 512
    float* c1   = f0 + 16794112;            // M*32
    float* mo   = na;

    ln1_kernel<<<MTOT, 128, 0, stream>>>(x, ln1_w, ln1_b, xn);
    gemm_mfma64<1><<<dim3(1, MTOT / 64), 256, 0, stream>>>(xn, conv1_w, conv1_b, c1, MTOT, 32, 128);
    gemm_mfma64<0><<<dim3(2, MTOT / 64), 256, 0, stream>>>(c1, conv2_w, conv2_b, t, MTOT, 128, 32);
    mean_partial_kernel<<<128, 128, 0, stream>>>(t, part);
    ca_kernel<<<NB, 128, 0, stream>>>(part, ca1_w, ca1_b, ca2_w, ca2_b, g2);
    gemm_mfma<0><<<dim3(6, MTOT / BM), 256, 0, stream>>>(xn, qkv_w, qkv_b, qkv, MTOT, 384, 128);
    na_tile_kernel<<<1024, 256, 0, stream>>>(qkv, rpb, na);
    gemm_mfma64<0><<<dim3(2, MTOT / 64), 256, 0, stream>>>(na, proj_w, proj_b, pe, MTOT, 128, 128);
    x2_kernel<<<MTOT, 128, 0, stream>>>(x, pe, t, g2, x2b);
    ln_rows_kernel<<<MTOT, 128, 0, stream>>>(x2b, ln2_w, ln2_b, pe);
    gemm_mfma<1><<<dim3(8, MTOT / BM), 256, 0, stream>>>(pe, fc1_w, fc1_b, hbuf, MTOT, 512, 128);
    gemm_mfma64<0><<<dim3(2, MTOT / 64), 256, 0, stream>>>(hbuf, fc2_w, fc2_b, mo, MTOT, 128, 512);
    final_kernel<<<MTOT, 128, 0, stream>>>(x2b, mo, out);
}

// Round 5
// 254.061 us; speedup vs baseline: 1.7963x; 1.1463x over previous
//
#include <hip/hip_runtime.h>
#include <hip/hip_bf16.h>
#include <math.h>

#define NB 4
#define CC 128
#define HH 64
#define WW 64
#define HEADS 4
#define KS 7
#define DD 32
#define HW 4096
#define MTOT 16384   // NB*HW

typedef unsigned short BF;
typedef short short8 __attribute__((ext_vector_type(8)));
typedef float floatx4 __attribute__((ext_vector_type(4)));

__device__ __forceinline__ float gelu_f(float x) {
    return 0.5f * x * (1.0f + erff(x * 0.70710678118654752440f));
}

__device__ __forceinline__ BF f2bf(float f) {
    union { float f; unsigned u; } a; a.f = f;
    unsigned u = a.u;
    unsigned r = u + 0x7FFFu + ((u >> 16) & 1u);   // RNE
    return (BF)(r >> 16);
}

__device__ __forceinline__ float bflo(unsigned p) { return __uint_as_float(p << 16); }
__device__ __forceinline__ float bfhi(unsigned p) { return __uint_as_float(p & 0xffff0000u); }

// ---------------- block reduce (128 threads = 2 waves) ----------------
__device__ __forceinline__ float block_sum_128(float v, float* tmp) {
    #pragma unroll
    for (int off = 32; off; off >>= 1) v += __shfl_xor(v, off);
    __syncthreads();
    if ((threadIdx.x & 63) == 0) tmp[threadIdx.x >> 6] = v;
    __syncthreads();
    return tmp[0] + tmp[1];
}

// ---------------- LN1: NCHW -> NHWC bf16 rows; also zeroes part -------
__global__ __launch_bounds__(128) void ln1_kernel(
    const float* __restrict__ x, const float* __restrict__ w,
    const float* __restrict__ b, BF* __restrict__ out,
    float* __restrict__ part)
{
    __shared__ float tmp[2];
    int m = blockIdx.x;
    int c = threadIdx.x;
    int n = m >> 12;
    int p = m & 4095;
    if (m < 4) part[m * CC + c] = 0.f;      // zero CA partials (used later)
    float v = x[(size_t)(n * CC + c) * HW + p];
    float mu = block_sum_128(v, tmp) * (1.0f / CC);
    float d = v - mu;
    float var = block_sum_128(d * d, tmp) * (1.0f / CC);
    float r = rsqrtf(var + 1e-5f);
    out[(size_t)m * CC + c] = f2bf(d * r * w[c] + b[c]);
}

// ---------------- bf16-A MFMA GEMM, BM=64/BN=64, BK=32 ----------------
// A (M,K) bf16 row-major, B (K,N) f32, bias f32.
// OUT: 0 = f32 C, 1 = bf16 C, 2 = NCHW final (C = acc+bias+x2b, transposed)
// REDUCE: atomicAdd per-column sums (over rows) into part[n*CC + col]
#define BK 32
#define LDK 40   // padded LDS row (bf16 elems; 80 B)
template<int ACT, int OUT, int REDUCE>
__global__ __launch_bounds__(256) void gemm64(
    const BF* __restrict__ A, const float* __restrict__ B,
    const float* __restrict__ bias, void* __restrict__ Cout,
    const float* __restrict__ x2b, float* __restrict__ part,
    int M, int N, int K)
{
    __shared__ __align__(16) BF Alds[64][LDK];
    __shared__ __align__(16) BF Blds[64][LDK];   // [n][k]
    __shared__ float red[4][64];

    const int t    = threadIdx.x;
    const int w    = t >> 6;
    const int lane = t & 63;
    const int q    = lane >> 4;
    const int r16  = lane & 15;
    const int row0 = blockIdx.y * 64;
    const int col0 = blockIdx.x * 64;

    floatx4 acc[4] = {};

    const int ar = t >> 2;            // 0..63
    const int ak = (t & 3) * 8;       // 0,8,16,24
    const int bk = t >> 3;            // 0..31
    const int bn = (t & 7) * 8;       // 0..56

    for (int k0 = 0; k0 < K; k0 += BK) {
        // A: 64x32 bf16 copy
        *(short8*)(&Alds[ar][ak]) =
            *(const short8*)(A + (size_t)(row0 + ar) * K + k0 + ak);
        // B: 32x64 f32 -> bf16 transposed [n][k]
        {
            const float* src = B + (size_t)(k0 + bk) * N + col0 + bn;
            if (col0 + bn + 8 <= N) {
                float4 b0 = *(const float4*)(src);
                float4 b1 = *(const float4*)(src + 4);
                Blds[bn + 0][bk] = f2bf(b0.x); Blds[bn + 1][bk] = f2bf(b0.y);
                Blds[bn + 2][bk] = f2bf(b0.z); Blds[bn + 3][bk] = f2bf(b0.w);
                Blds[bn + 4][bk] = f2bf(b1.x); Blds[bn + 5][bk] = f2bf(b1.y);
                Blds[bn + 6][bk] = f2bf(b1.z); Blds[bn + 7][bk] = f2bf(b1.w);
            } else {
                #pragma unroll
                for (int u = 0; u < 8; u++) {
                    int col = col0 + bn + u;
                    Blds[bn + u][bk] = (col < N) ? f2bf(src[u]) : (BF)0;
                }
            }
        }
        __syncthreads();

        short8 af = *(const short8*)(&Alds[w * 16 + r16][q * 8]);
        short8 bfm[4];
        #pragma unroll
        for (int nt = 0; nt < 4; nt++)
            bfm[nt] = *(const short8*)(&Blds[nt * 16 + r16][q * 8]);
        #pragma unroll
        for (int nt = 0; nt < 4; nt++)
            acc[nt] = __builtin_amdgcn_mfma_f32_16x16x32_bf16(af, bfm[nt], acc[nt], 0, 0, 0);
        __syncthreads();
    }

    float rs[4] = {0.f, 0.f, 0.f, 0.f};
    #pragma unroll
    for (int nt = 0; nt < 4; nt++) {
        int col = col0 + nt * 16 + r16;
        if (col < N) {
            float bv = bias[col];
            #pragma unroll
            for (int reg = 0; reg < 4; reg++) {
                int row = row0 + w * 16 + q * 4 + reg;
                float v = acc[nt][reg] + bv;
                if (ACT == 1) v = gelu_f(v);
                if (OUT == 0) {
                    ((float*)Cout)[(size_t)row * N + col] = v;
                } else if (OUT == 1) {
                    ((BF*)Cout)[(size_t)row * N + col] = f2bf(v);
                } else {
                    int p = row & 4095, n = row >> 12;
                    ((float*)Cout)[(size_t)(n * CC + col) * HW + p] =
                        v + x2b[(size_t)row * CC + col];
                }
                if (REDUCE) rs[nt] += v;
            }
        }
    }

    if (REDUCE) {
        #pragma unroll
        for (int nt = 0; nt < 4; nt++) {
            float s = rs[nt];
            s += __shfl_xor(s, 16);
            s += __shfl_xor(s, 32);
            if (lane < 16) red[w][nt * 16 + r16] = s;
        }
        __syncthreads();
        if (t < 64) {
            float cs = red[0][t] + red[1][t] + red[2][t] + red[3][t];
            atomicAdd(&part[(row0 >> 12) * CC + col0 + t], cs);
        }
    }
}

// ---------------- channel-attention tiny MLP --------------------------
__global__ __launch_bounds__(128) void ca_kernel(
    const float* __restrict__ part,
    const float* __restrict__ ca1_w, const float* __restrict__ ca1_b,
    const float* __restrict__ ca2_w, const float* __restrict__ ca2_b,
    float* __restrict__ g2)
{
    __shared__ float gs[128];
    __shared__ float h1[7];
    int n = blockIdx.x;
    int c = threadIdx.x;
    float gm = part[(size_t)n * CC + c] * (1.0f / HW);
    gs[c] = gm;
    __syncthreads();
    if (c < 7) {
        float a = ca1_b[c];
        for (int k = 0; k < 128; k++) a += gs[k] * ca1_w[k * 7 + c];
        h1[c] = fmaxf(a, 0.f);
    }
    __syncthreads();
    float o = ca2_b[c];
    #pragma unroll
    for (int r = 0; r < 7; r++) o += h1[r] * ca2_w[r * 128 + c];
    g2[(size_t)n * CC + c] = 1.0f / (1.0f + expf(-o));
}

// ---------------- tiled neighborhood attention (bf16 qkv in/out) ------
// block = 8x8 query tile x 1 head; 512 threads = 8 waves x 8 queries.
// qkv is bf16 (M,384); staging is pure dword copies (no converts).
// Kb32[dpair][key] stride 210; Vb32[key][dpair]; Qb32 unscaled (scale
// applied to scores). Output bf16-packed dwords.
__global__ __launch_bounds__(512) void na_tile_kernel(
    const BF* __restrict__ qkv, const float* __restrict__ rpb,
    unsigned* __restrict__ outp)
{
    __shared__ unsigned Kb32[16][210];
    __shared__ unsigned Vb32[196][16];
    __shared__ unsigned Qb32[64][16];
    __shared__ float rb[169];
    __shared__ float sp[8][64];

    const int b    = blockIdx.x;
    const int h    = b & 3;
    const int tile = b >> 2;
    const int n    = tile >> 6;
    const int ti   = (tile >> 3) & 7;
    const int tj   = tile & 7;
    const int t    = threadIdx.x;
    const int w    = t >> 6;
    const int lane = t & 63;

    const int i0 = ti * 8, j0 = tj * 8;
    const int wi0 = max(i0 - 3, 0);
    const int wj0 = max(j0 - 3, 0);
    const int R  = min(wi0 + 13, HH - 1) - wi0 + 1;
    const int Rj = min(wj0 + 13, WW - 1) - wj0 + 1;

    // ---- stage K,V: 196 pixels x 8 uint4 chunks (4 K, 4 V) ----
    for (int idx = t; idx < 196 * 8; idx += 512) {
        int pixel = idx >> 3, ch = idx & 7;
        int pr = pixel / 14, pc = pixel % 14;
        if (pr < R && pc < Rj) {
            int seg = ch >> 2, c4 = ch & 3;
            const BF* src = qkv
                + ((size_t)((n * HH + wi0 + pr) * WW + wj0 + pc)) * 384
                + 128 + seg * 128 + h * DD + c4 * 8;
            uint4 v = *(const uint4*)src;
            if (seg == 0) {
                Kb32[c4 * 4 + 0][pixel] = v.x;
                Kb32[c4 * 4 + 1][pixel] = v.y;
                Kb32[c4 * 4 + 2][pixel] = v.z;
                Kb32[c4 * 4 + 3][pixel] = v.w;
            } else {
                *(uint4*)&Vb32[pixel][c4 * 4] = v;
            }
        }
    }
    // ---- stage Q: 64 q x 4 uint4 chunks ----
    for (int idx = t; idx < 64 * 4; idx += 512) {
        int q = idx >> 2, c4 = idx & 3;
        int qi = q >> 3, qj = q & 7;
        size_t m = (size_t)((n * HH + i0 + qi) * WW + j0 + qj);
        *(uint4*)&Qb32[q][c4 * 4] = *(const uint4*)(qkv + m * 384 + h * DD + c4 * 8);
    }
    if (t < 169) rb[t] = rpb[h * 169 + t];
    __syncthreads();

    for (int qq = 0; qq < 8; qq++) {
        int q  = w * 8 + qq;
        int qi = q >> 3, qj = q & 7;
        int i = i0 + qi, j = j0 + qj;
        int ni = min(max(i - 3, 0), HH - KS);
        int nj = min(max(j - 3, 0), WW - KS);
        int keybase = (ni - wi0) * 14 + (nj - wj0);

        unsigned qp[16];
        #pragma unroll
        for (int u = 0; u < 16; u++) qp[u] = Qb32[q][u];   // broadcast

        int aa = min(lane, KS * KS - 1);
        int ar = aa / KS, ac = aa % KS;
        int key = keybase + ar * 14 + ac;
        float s = 0.f;
        #pragma unroll
        for (int dp = 0; dp < 16; dp++) {
            unsigned kv = Kb32[dp][key];
            s += bflo(qp[dp]) * bflo(kv);
            s += bfhi(qp[dp]) * bfhi(kv);
        }
        s = s * 0.17677669529663688110f + rb[(ni - i + 6 + ar) * 13 + (nj - j + 6 + ac)];
        float score = (lane < KS * KS) ? s : -INFINITY;

        float mx = score;
        #pragma unroll
        for (int off = 32; off; off >>= 1) mx = fmaxf(mx, __shfl_xor(mx, off));
        float e = (lane < KS * KS) ? __expf(score - mx) : 0.f;
        float sm = e;
        #pragma unroll
        for (int off = 32; off; off >>= 1) sm += __shfl_xor(sm, off);
        sp[w][lane] = e / sm;          // same-wave write->read

        // ---- PV: lane = (quarter, dpair); keys stride 4 ----
        int quarter = lane >> 4, dpv = lane & 15;
        float accl = 0.f, acch = 0.f;
        int rr = 0, cc = quarter;
        #pragma unroll
        for (int it = 0; it < 13; it++) {
            int a4 = 4 * it + quarter;
            if (a4 < 49) {
                float p = sp[w][a4];
                unsigned pv = Vb32[keybase + rr * 14 + cc][dpv];
                accl += p * bflo(pv);
                acch += p * bfhi(pv);
            }
            cc += 4; if (cc >= KS) { cc -= KS; rr++; }
        }
        accl += __shfl_xor(accl, 16); accl += __shfl_xor(accl, 32);
        acch += __shfl_xor(acch, 16); acch += __shfl_xor(acch, 32);
        if (lane < 16) {
            size_t m = (size_t)((n * HH + i) * WW + j);
            unsigned pk = ((unsigned)f2bf(accl)) | (((unsigned)f2bf(acch)) << 16);
            outp[m * 64 + h * 16 + dpv] = pk;
        }
    }
}

// ---------------- fused x2 + LN2 --------------------------------------
// x2 = shortcut(NCHW) + proj + 0.02*t*g ; store f32 x2b and bf16 LN2(x2)
__global__ __launch_bounds__(128) void x2ln2_kernel(
    const float* __restrict__ x, const float* __restrict__ pe,
    const float* __restrict__ t, const float* __restrict__ g2,
    const float* __restrict__ w2, const float* __restrict__ b2,
    float* __restrict__ x2b, BF* __restrict__ lnout)
{
    __shared__ float tmp[2];
    int m = blockIdx.x;
    int c = threadIdx.x;
    int n = m >> 12;
    int p = m & 4095;
    size_t idx = (size_t)m * CC + c;
    float v = x[(size_t)(n * CC + c) * HW + p] + pe[idx]
            + 0.02f * t[idx] * g2[(size_t)n * CC + c];
    x2b[idx] = v;
    float mu = block_sum_128(v, tmp) * (1.0f / CC);
    float d = v - mu;
    float var = block_sum_128(d * d, tmp) * (1.0f / CC);
    float r = rsqrtf(var + 1e-5f);
    lnout[idx] = f2bf(d * r * w2[c] + b2[c]);
}

extern "C" void kernel_launch(void* const* d_in, const int* in_sizes, int n_in,
                              void* d_out, int out_size, void* d_ws, size_t ws_size,
                              hipStream_t stream)
{
    const float* x       = (const float*)d_in[0];
    const float* ln1_w   = (const float*)d_in[1];
    const float* ln1_b   = (const float*)d_in[2];
    const float* ln2_w   = (const float*)d_in[3];
    const float* ln2_b   = (const float*)d_in[4];
    const float* qkv_w   = (const float*)d_in[5];
    const float* qkv_b   = (const float*)d_in[6];
    const float* proj_w  = (const float*)d_in[7];
    const float* proj_b  = (const float*)d_in[8];
    const float* rpb     = (const float*)d_in[9];
    const float* conv1_w = (const float*)d_in[10];
    const float* conv1_b = (const float*)d_in[11];
    const float* conv2_w = (const float*)d_in[12];
    const float* conv2_b = (const float*)d_in[13];
    const float* ca1_w   = (const float*)d_in[14];
    const float* ca1_b   = (const float*)d_in[15];
    const float* ca2_w   = (const float*)d_in[16];
    const float* ca2_b   = (const float*)d_in[17];
    const float* fc1_w   = (const float*)d_in[18];
    const float* fc1_b   = (const float*)d_in[19];
    const float* fc2_w   = (const float*)d_in[20];
    const float* fc2_b   = (const float*)d_in[21];
    float* out = (float*)d_out;

    // workspace layout (bytes). hbuf_bf overlays xn_bf+qkv_bf (dead by fc1).
    char* ws = (char*)d_ws;
    BF*    xn_bf   = (BF*)(ws);                  // M*128*2 = 4,194,304
    BF*    qkv_bf  = (BF*)(ws + 4194304);        // M*384*2 = 12,582,912
    BF*    hbuf_bf = (BF*)(ws);                  // M*512*2 = 16,777,216 (overlay)
    float* t       = (float*)(ws + 16777216);    // M*128*4
    float* pe      = (float*)(ws + 25165824);    // M*128*4
    float* x2b     = (float*)(ws + 33554432);    // M*128*4
    BF*    na_bf   = (BF*)(ws + 41943040);       // M*128*2
    BF*    ln2_bf  = (BF*)(ws + 46137344);       // M*128*2
    BF*    c1_bf   = (BF*)(ws + 50331648);       // M*32*2
    float* part    = (float*)(ws + 51380224);    // 4*128*4
    float* g2      = (float*)(ws + 51382272);    // 4*128*4

    // 1. LN1 (NCHW -> bf16 NHWC rows; zeroes part)
    ln1_kernel<<<MTOT, 128, 0, stream>>>(x, ln1_w, ln1_b, xn_bf, part);
    // 2. conv1: (M,128)@(128,32)+gelu -> bf16
    gemm64<1,1,0><<<dim3(1, MTOT/64), 256, 0, stream>>>(xn_bf, conv1_w, conv1_b, c1_bf, nullptr, nullptr, MTOT, 32, 128);
    // 3. conv2: (M,32)@(32,128) -> f32 t, + fused column sums into part
    gemm64<0,0,1><<<dim3(2, MTOT/64), 256, 0, stream>>>(c1_bf, conv2_w, conv2_b, t, nullptr, part, MTOT, 128, 32);
    // 4. channel-attention gate
    ca_kernel<<<NB, 128, 0, stream>>>(part, ca1_w, ca1_b, ca2_w, ca2_b, g2);
    // 5. qkv: (M,128)@(128,384) -> bf16
    gemm64<0,1,0><<<dim3(6, MTOT/64), 256, 0, stream>>>(xn_bf, qkv_w, qkv_b, qkv_bf, nullptr, nullptr, MTOT, 384, 128);
    // 6. neighborhood attention (8x8 tile x head, 8 waves)
    na_tile_kernel<<<1024, 512, 0, stream>>>(qkv_bf, rpb, (unsigned*)na_bf);
    // 7. proj: (M,128)@(128,128) -> f32
    gemm64<0,0,0><<<dim3(2, MTOT/64), 256, 0, stream>>>(na_bf, proj_w, proj_b, pe, nullptr, nullptr, MTOT, 128, 128);
    // 8. x2 = shortcut + proj + 0.02*t*g ; LN2 -> bf16
    x2ln2_kernel<<<MTOT, 128, 0, stream>>>(x, pe, t, g2, ln2_w, ln2_b, x2b, ln2_bf);
    // 9. fc1: (M,128)@(128,512)+gelu -> bf16 (overlays xn/qkv)
    gemm64<1,1,0><<<dim3(8, MTOT/64), 256, 0, stream>>>(ln2_bf, fc1_w, fc1_b, hbuf_bf, nullptr, nullptr, MTOT, 512, 128);
    // 10. fc2: (M,512)@(512,128) + x2b, fused NHWC->NCHW store
    gemm64<0,2,0><<<dim3(2, MTOT/64), 256, 0, stream>>>(hbuf_bf, fc2_w, fc2_b, out, x2b, nullptr, MTOT, 128, 512);
}

// Round 6
// 231.417 us; speedup vs baseline: 1.9720x; 1.0978x over previous
//
#include <hip/hip_runtime.h>
#include <hip/hip_bf16.h>
#include <math.h>

#define NB 4
#define CC 128
#define HH 64
#define WW 64
#define HEADS 4
#define KS 7
#define DD 32
#define HW 4096
#define MTOT 16384   // NB*HW

typedef unsigned short BF;
typedef short short8 __attribute__((ext_vector_type(8)));
typedef float floatx4 __attribute__((ext_vector_type(4)));

__device__ __forceinline__ float gelu_f(float x) {
    return 0.5f * x * (1.0f + erff(x * 0.70710678118654752440f));
}

__device__ __forceinline__ BF f2bf(float f) {
    union { float f; unsigned u; } a; a.f = f;
    unsigned u = a.u;
    unsigned r = u + 0x7FFFu + ((u >> 16) & 1u);   // RNE
    return (BF)(r >> 16);
}

__device__ __forceinline__ float bflo(unsigned p) { return __uint_as_float(p << 16); }
__device__ __forceinline__ float bfhi(unsigned p) { return __uint_as_float(p & 0xffff0000u); }

// ---------------- block reduce (128 threads = 2 waves) ----------------
__device__ __forceinline__ float block_sum_128(float v, float* tmp) {
    #pragma unroll
    for (int off = 32; off; off >>= 1) v += __shfl_xor(v, off);
    __syncthreads();
    if ((threadIdx.x & 63) == 0) tmp[threadIdx.x >> 6] = v;
    __syncthreads();
    return tmp[0] + tmp[1];
}

// ---------------- LN1: NCHW -> NHWC bf16 rows; also zeroes part -------
__global__ __launch_bounds__(128) void ln1_kernel(
    const float* __restrict__ x, const float* __restrict__ w,
    const float* __restrict__ b, BF* __restrict__ out,
    float* __restrict__ part)
{
    __shared__ float tmp[2];
    int m = blockIdx.x;
    int c = threadIdx.x;
    int n = m >> 12;
    int p = m & 4095;
    if (m < 4) part[m * CC + c] = 0.f;      // zero CA partials
    float v = x[(size_t)(n * CC + c) * HW + p];
    float mu = block_sum_128(v, tmp) * (1.0f / CC);
    float d = v - mu;
    float var = block_sum_128(d * d, tmp) * (1.0f / CC);
    float r = rsqrtf(var + 1e-5f);
    out[(size_t)m * CC + c] = f2bf(d * r * w[c] + b[c]);
}

// ---------------- bf16-A MFMA GEMM, BM=64/BN=64, BK=32 ----------------
// OUT: 0 = f32 C, 1 = bf16 C, 2 = NCHW final (C = acc+bias+x2b, transposed)
#define BK 32
#define LDK 40   // padded LDS row (bf16 elems; 80 B)
template<int ACT, int OUT>
__global__ __launch_bounds__(256) void gemm64(
    const BF* __restrict__ A, const float* __restrict__ B,
    const float* __restrict__ bias, void* __restrict__ Cout,
    const float* __restrict__ x2b,
    int M, int N, int K)
{
    __shared__ __align__(16) BF Alds[64][LDK];
    __shared__ __align__(16) BF Blds[64][LDK];   // [n][k]

    const int t    = threadIdx.x;
    const int w    = t >> 6;
    const int lane = t & 63;
    const int q    = lane >> 4;
    const int r16  = lane & 15;
    const int row0 = blockIdx.y * 64;
    const int col0 = blockIdx.x * 64;

    floatx4 acc[4] = {};

    const int ar = t >> 2;            // 0..63
    const int ak = (t & 3) * 8;       // 0,8,16,24
    const int bk = t >> 3;            // 0..31
    const int bn = (t & 7) * 8;       // 0..56

    for (int k0 = 0; k0 < K; k0 += BK) {
        *(short8*)(&Alds[ar][ak]) =
            *(const short8*)(A + (size_t)(row0 + ar) * K + k0 + ak);
        {
            const float* src = B + (size_t)(k0 + bk) * N + col0 + bn;
            if (col0 + bn + 8 <= N) {
                float4 b0 = *(const float4*)(src);
                float4 b1 = *(const float4*)(src + 4);
                Blds[bn + 0][bk] = f2bf(b0.x); Blds[bn + 1][bk] = f2bf(b0.y);
                Blds[bn + 2][bk] = f2bf(b0.z); Blds[bn + 3][bk] = f2bf(b0.w);
                Blds[bn + 4][bk] = f2bf(b1.x); Blds[bn + 5][bk] = f2bf(b1.y);
                Blds[bn + 6][bk] = f2bf(b1.z); Blds[bn + 7][bk] = f2bf(b1.w);
            } else {
                #pragma unroll
                for (int u = 0; u < 8; u++) {
                    int col = col0 + bn + u;
                    Blds[bn + u][bk] = (col < N) ? f2bf(src[u]) : (BF)0;
                }
            }
        }
        __syncthreads();

        short8 af = *(const short8*)(&Alds[w * 16 + r16][q * 8]);
        short8 bfm[4];
        #pragma unroll
        for (int nt = 0; nt < 4; nt++)
            bfm[nt] = *(const short8*)(&Blds[nt * 16 + r16][q * 8]);
        #pragma unroll
        for (int nt = 0; nt < 4; nt++)
            acc[nt] = __builtin_amdgcn_mfma_f32_16x16x32_bf16(af, bfm[nt], acc[nt], 0, 0, 0);
        __syncthreads();
    }

    #pragma unroll
    for (int nt = 0; nt < 4; nt++) {
        int col = col0 + nt * 16 + r16;
        if (col < N) {
            float bv = bias[col];
            #pragma unroll
            for (int reg = 0; reg < 4; reg++) {
                int row = row0 + w * 16 + q * 4 + reg;
                float v = acc[nt][reg] + bv;
                if (ACT == 1) v = gelu_f(v);
                if (OUT == 0) {
                    ((float*)Cout)[(size_t)row * N + col] = v;
                } else if (OUT == 1) {
                    ((BF*)Cout)[(size_t)row * N + col] = f2bf(v);
                } else {
                    int p = row & 4095, n = row >> 12;
                    ((float*)Cout)[(size_t)(n * CC + col) * HW + p] =
                        v + x2b[(size_t)row * CC + col];
                }
            }
        }
    }
}

// ---------------- fused conv1+gelu+conv2 (+column sums) ---------------
// One block = 64 rows; two MFMA stages through LDS. Grid 256.
#define LDK128 136
__global__ __launch_bounds__(256) void conv_fused(
    const BF* __restrict__ xn, const float* __restrict__ w1,
    const float* __restrict__ b1, const float* __restrict__ w2,
    const float* __restrict__ b2, float* __restrict__ tout,
    float* __restrict__ part)
{
    __shared__ __align__(16) BF Xl[64][LDK128];    // 17.4 KB
    __shared__ __align__(16) BF W1l[32][LDK128];   // 8.7 KB  [n][k]
    __shared__ __align__(16) BF Hl[64][LDK];       // 5 KB
    __shared__ __align__(16) BF W2l[128][LDK];     // 10 KB   [n][k]
    __shared__ float red[4][128];

    const int t_ = threadIdx.x;
    const int w = t_ >> 6, lane = t_ & 63, q = lane >> 4, r16 = lane & 15;
    const int row0 = blockIdx.x * 64;

    {   // stage X: 64 rows x 128 k (bf16 copy)
        int r = t_ >> 2, k0 = (t_ & 3) * 32;
        const BF* src = xn + (size_t)(row0 + r) * CC + k0;
        #pragma unroll
        for (int u = 0; u < 4; u++)
            *(short8*)(&Xl[r][k0 + u * 8]) = *(const short8*)(src + u * 8);
    }
    {   // stage W1 (128,32) f32 -> [n][k] bf16
        int kk = t_ >> 1, nn = (t_ & 1) * 16;
        const float* src = w1 + (size_t)kk * 32 + nn;
        #pragma unroll
        for (int u = 0; u < 16; u++) W1l[nn + u][kk] = f2bf(src[u]);
    }
    {   // stage W2 (32,128) f32 -> [n][k] bf16
        int kk = t_ >> 3, n0 = (t_ & 7) * 16;
        const float* src = w2 + (size_t)kk * 128 + n0;
        #pragma unroll
        for (int u = 0; u < 16; u++) W2l[n0 + u][kk] = f2bf(src[u]);
    }
    __syncthreads();

    // stage 1: h = gelu(X @ w1 + b1) -> Hl (wave: 16 rows x 32 cols)
    floatx4 a1[2] = {};
    #pragma unroll
    for (int ki = 0; ki < 4; ki++) {
        short8 af = *(const short8*)(&Xl[w * 16 + r16][ki * 32 + q * 8]);
        #pragma unroll
        for (int nt = 0; nt < 2; nt++) {
            short8 bfm = *(const short8*)(&W1l[nt * 16 + r16][ki * 32 + q * 8]);
            a1[nt] = __builtin_amdgcn_mfma_f32_16x16x32_bf16(af, bfm, a1[nt], 0, 0, 0);
        }
    }
    #pragma unroll
    for (int nt = 0; nt < 2; nt++) {
        int col = nt * 16 + r16;
        float bv = b1[col];
        #pragma unroll
        for (int reg = 0; reg < 4; reg++)
            Hl[w * 16 + q * 4 + reg][col] = f2bf(gelu_f(a1[nt][reg] + bv));
    }
    __syncthreads();

    // stage 2: t = H @ w2 + b2 (wave: 16 rows x 128 cols) + column sums
    floatx4 a2[8] = {};
    {
        short8 af = *(const short8*)(&Hl[w * 16 + r16][q * 8]);
        #pragma unroll
        for (int nt = 0; nt < 8; nt++) {
            short8 bfm = *(const short8*)(&W2l[nt * 16 + r16][q * 8]);
            a2[nt] = __builtin_amdgcn_mfma_f32_16x16x32_bf16(af, bfm, a2[nt], 0, 0, 0);
        }
    }
    #pragma unroll
    for (int nt = 0; nt < 8; nt++) {
        int col = nt * 16 + r16;
        float bv = b2[col];
        float s = 0.f;
        #pragma unroll
        for (int reg = 0; reg < 4; reg++) {
            int row = row0 + w * 16 + q * 4 + reg;
            float v = a2[nt][reg] + bv;
            tout[(size_t)row * CC + col] = v;
            s += v;
        }
        s += __shfl_xor(s, 16);
        s += __shfl_xor(s, 32);
        if (lane < 16) red[w][col] = s;
    }
    __syncthreads();
    if (t_ < 128) {
        float cs = red[0][t_] + red[1][t_] + red[2][t_] + red[3][t_];
        atomicAdd(&part[(row0 >> 12) * CC + t_], cs);
    }
}

// ---------------- channel-attention tiny MLP --------------------------
__global__ __launch_bounds__(128) void ca_kernel(
    const float* __restrict__ part,
    const float* __restrict__ ca1_w, const float* __restrict__ ca1_b,
    const float* __restrict__ ca2_w, const float* __restrict__ ca2_b,
    float* __restrict__ g2)
{
    __shared__ float gs[128];
    __shared__ float h1[7];
    int n = blockIdx.x;
    int c = threadIdx.x;
    float gm = part[(size_t)n * CC + c] * (1.0f / HW);
    gs[c] = gm;
    __syncthreads();
    if (c < 7) {
        float a = ca1_b[c];
        for (int k = 0; k < 128; k++) a += gs[k] * ca1_w[k * 7 + c];
        h1[c] = fmaxf(a, 0.f);
    }
    __syncthreads();
    float o = ca2_b[c];
    #pragma unroll
    for (int r = 0; r < 7; r++) o += h1[r] * ca2_w[r * 128 + c];
    g2[(size_t)n * CC + c] = 1.0f / (1.0f + expf(-o));
}

// ---------------- tiled neighborhood attention (bf16 qkv in/out) ------
__global__ __launch_bounds__(512) void na_tile_kernel(
    const BF* __restrict__ qkv, const float* __restrict__ rpb,
    unsigned* __restrict__ outp)
{
    __shared__ unsigned Kb32[16][210];
    __shared__ unsigned Vb32[196][16];
    __shared__ unsigned Qb32[64][16];
    __shared__ float rb[169];
    __shared__ float sp[8][64];

    const int b    = blockIdx.x;
    const int h    = b & 3;
    const int tile = b >> 2;
    const int n    = tile >> 6;
    const int ti   = (tile >> 3) & 7;
    const int tj   = tile & 7;
    const int t    = threadIdx.x;
    const int w    = t >> 6;
    const int lane = t & 63;

    const int i0 = ti * 8, j0 = tj * 8;
    const int wi0 = max(i0 - 3, 0);
    const int wj0 = max(j0 - 3, 0);
    const int R  = min(wi0 + 13, HH - 1) - wi0 + 1;
    const int Rj = min(wj0 + 13, WW - 1) - wj0 + 1;

    for (int idx = t; idx < 196 * 8; idx += 512) {
        int pixel = idx >> 3, ch = idx & 7;
        int pr = pixel / 14, pc = pixel % 14;
        if (pr < R && pc < Rj) {
            int seg = ch >> 2, c4 = ch & 3;
            const BF* src = qkv
                + ((size_t)((n * HH + wi0 + pr) * WW + wj0 + pc)) * 384
                + 128 + seg * 128 + h * DD + c4 * 8;
            uint4 v = *(const uint4*)src;
            if (seg == 0) {
                Kb32[c4 * 4 + 0][pixel] = v.x;
                Kb32[c4 * 4 + 1][pixel] = v.y;
                Kb32[c4 * 4 + 2][pixel] = v.z;
                Kb32[c4 * 4 + 3][pixel] = v.w;
            } else {
                *(uint4*)&Vb32[pixel][c4 * 4] = v;
            }
        }
    }
    for (int idx = t; idx < 64 * 4; idx += 512) {
        int q = idx >> 2, c4 = idx & 3;
        int qi = q >> 3, qj = q & 7;
        size_t m = (size_t)((n * HH + i0 + qi) * WW + j0 + qj);
        *(uint4*)&Qb32[q][c4 * 4] = *(const uint4*)(qkv + m * 384 + h * DD + c4 * 8);
    }
    if (t < 169) rb[t] = rpb[h * 169 + t];
    __syncthreads();

    for (int qq = 0; qq < 8; qq++) {
        int q  = w * 8 + qq;
        int qi = q >> 3, qj = q & 7;
        int i = i0 + qi, j = j0 + qj;
        int ni = min(max(i - 3, 0), HH - KS);
        int nj = min(max(j - 3, 0), WW - KS);
        int keybase = (ni - wi0) * 14 + (nj - wj0);

        unsigned qp[16];
        #pragma unroll
        for (int u = 0; u < 16; u++) qp[u] = Qb32[q][u];

        int aa = min(lane, KS * KS - 1);
        int ar = aa / KS, ac = aa % KS;
        int key = keybase + ar * 14 + ac;
        float s = 0.f;
        #pragma unroll
        for (int dp = 0; dp < 16; dp++) {
            unsigned kv = Kb32[dp][key];
            s += bflo(qp[dp]) * bflo(kv);
            s += bfhi(qp[dp]) * bfhi(kv);
        }
        s = s * 0.17677669529663688110f + rb[(ni - i + 6 + ar) * 13 + (nj - j + 6 + ac)];
        float score = (lane < KS * KS) ? s : -INFINITY;

        float mx = score;
        #pragma unroll
        for (int off = 32; off; off >>= 1) mx = fmaxf(mx, __shfl_xor(mx, off));
        float e = (lane < KS * KS) ? __expf(score - mx) : 0.f;
        float sm = e;
        #pragma unroll
        for (int off = 32; off; off >>= 1) sm += __shfl_xor(sm, off);
        sp[w][lane] = e / sm;

        int quarter = lane >> 4, dpv = lane & 15;
        float accl = 0.f, acch = 0.f;
        int rr = 0, cc = quarter;
        #pragma unroll
        for (int it = 0; it < 13; it++) {
            int a4 = 4 * it + quarter;
            if (a4 < 49) {
                float p = sp[w][a4];
                unsigned pv = Vb32[keybase + rr * 14 + cc][dpv];
                accl += p * bflo(pv);
                acch += p * bfhi(pv);
            }
            cc += 4; if (cc >= KS) { cc -= KS; rr++; }
        }
        accl += __shfl_xor(accl, 16); accl += __shfl_xor(accl, 32);
        acch += __shfl_xor(acch, 16); acch += __shfl_xor(acch, 32);
        if (lane < 16) {
            size_t m = (size_t)((n * HH + i) * WW + j);
            unsigned pk = ((unsigned)f2bf(accl)) | (((unsigned)f2bf(acch)) << 16);
            outp[m * 64 + h * 16 + dpv] = pk;
        }
    }
}

// ---------------- fused proj GEMM + x2 residual + LN2 -----------------
// Row-complete: BM=64, BN=128 (full channel width) so LN2 runs in-register.
// x2 = x(NCHW) + proj + 0.02*t*g2 -> x2b f32 ; LN2(x2) -> bf16
__global__ __launch_bounds__(256) void projx2ln2(
    const BF* __restrict__ A, const float* __restrict__ Bw,
    const float* __restrict__ bias, const float* __restrict__ x,
    const float* __restrict__ tbuf, const float* __restrict__ g2,
    const float* __restrict__ w2, const float* __restrict__ b2,
    float* __restrict__ x2b, BF* __restrict__ lnout)
{
    __shared__ __align__(16) BF Alds[64][LDK];
    __shared__ __align__(16) BF Blds[128][LDK];   // [n][k]

    const int t_ = threadIdx.x;
    const int w = t_ >> 6, lane = t_ & 63, q = lane >> 4, r16 = lane & 15;
    const int row0 = blockIdx.x * 64;
    const int n = row0 >> 12;

    floatx4 acc[8] = {};
    const int ar = t_ >> 2, ak = (t_ & 3) * 8;
    const int bkk = t_ >> 3, bn0 = (t_ & 7) * 16;

    for (int k0 = 0; k0 < 128; k0 += 32) {
        *(short8*)(&Alds[ar][ak]) =
            *(const short8*)(A + (size_t)(row0 + ar) * CC + k0 + ak);
        {
            const float* src = Bw + (size_t)(k0 + bkk) * CC + bn0;
            #pragma unroll
            for (int u = 0; u < 16; u++) Blds[bn0 + u][bkk] = f2bf(src[u]);
        }
        __syncthreads();
        short8 af = *(const short8*)(&Alds[w * 16 + r16][q * 8]);
        #pragma unroll
        for (int nt = 0; nt < 8; nt++) {
            short8 bfm = *(const short8*)(&Blds[nt * 16 + r16][q * 8]);
            acc[nt] = __builtin_amdgcn_mfma_f32_16x16x32_bf16(af, bfm, acc[nt], 0, 0, 0);
        }
        __syncthreads();
    }

    float s1[4] = {0.f, 0.f, 0.f, 0.f}, s2[4] = {0.f, 0.f, 0.f, 0.f};
    #pragma unroll
    for (int nt = 0; nt < 8; nt++) {
        int col = nt * 16 + r16;
        float bv = bias[col];
        float gv = g2[n * CC + col];
        #pragma unroll
        for (int reg = 0; reg < 4; reg++) {
            int row = row0 + w * 16 + q * 4 + reg;
            int p = row & 4095;
            float xv = x[(size_t)(n * CC + col) * HW + p];
            float tv = tbuf[(size_t)row * CC + col];
            float v = acc[nt][reg] + bv + xv + 0.02f * tv * gv;
            acc[nt][reg] = v;
            s1[reg] += v;
            s2[reg] += v * v;
        }
    }
    #pragma unroll
    for (int reg = 0; reg < 4; reg++) {
        #pragma unroll
        for (int off = 8; off; off >>= 1) {
            s1[reg] += __shfl_xor(s1[reg], off);
            s2[reg] += __shfl_xor(s2[reg], off);
        }
    }
    float mu[4], rr[4];
    #pragma unroll
    for (int reg = 0; reg < 4; reg++) {
        mu[reg] = s1[reg] * (1.0f / CC);
        float var = s2[reg] * (1.0f / CC) - mu[reg] * mu[reg];
        rr[reg] = rsqrtf(var + 1e-5f);
    }
    #pragma unroll
    for (int nt = 0; nt < 8; nt++) {
        int col = nt * 16 + r16;
        float wv = w2[col], bv2 = b2[col];
        #pragma unroll
        for (int reg = 0; reg < 4; reg++) {
            int row = row0 + w * 16 + q * 4 + reg;
            float v = acc[nt][reg];
            x2b[(size_t)row * CC + col] = v;
            lnout[(size_t)row * CC + col] = f2bf((v - mu[reg]) * rr[reg] * wv + bv2);
        }
    }
}

extern "C" void kernel_launch(void* const* d_in, const int* in_sizes, int n_in,
                              void* d_out, int out_size, void* d_ws, size_t ws_size,
                              hipStream_t stream)
{
    const float* x       = (const float*)d_in[0];
    const float* ln1_w   = (const float*)d_in[1];
    const float* ln1_b   = (const float*)d_in[2];
    const float* ln2_w   = (const float*)d_in[3];
    const float* ln2_b   = (const float*)d_in[4];
    const float* qkv_w   = (const float*)d_in[5];
    const float* qkv_b   = (const float*)d_in[6];
    const float* proj_w  = (const float*)d_in[7];
    const float* proj_b  = (const float*)d_in[8];
    const float* rpb     = (const float*)d_in[9];
    const float* conv1_w = (const float*)d_in[10];
    const float* conv1_b = (const float*)d_in[11];
    const float* conv2_w = (const float*)d_in[12];
    const float* conv2_b = (const float*)d_in[13];
    const float* ca1_w   = (const float*)d_in[14];
    const float* ca1_b   = (const float*)d_in[15];
    const float* ca2_w   = (const float*)d_in[16];
    const float* ca2_b   = (const float*)d_in[17];
    const float* fc1_w   = (const float*)d_in[18];
    const float* fc1_b   = (const float*)d_in[19];
    const float* fc2_w   = (const float*)d_in[20];
    const float* fc2_b   = (const float*)d_in[21];
    float* out = (float*)d_out;

    // workspace (bytes). hbuf_bf overlays xn_bf+qkv_bf (both dead by fc1).
    char* ws = (char*)d_ws;
    BF*    xn_bf   = (BF*)(ws);                  // M*128*2 = 4 MB
    BF*    qkv_bf  = (BF*)(ws + 4194304);        // M*384*2 = 12 MB
    BF*    hbuf_bf = (BF*)(ws);                  // M*512*2 = 16 MB (overlay)
    float* t       = (float*)(ws + 16777216);    // M*128*4 = 8 MB
    float* x2b     = (float*)(ws + 25165824);    // M*128*4 = 8 MB
    BF*    na_bf   = (BF*)(ws + 33554432);       // M*128*2 = 4 MB
    BF*    ln2_bf  = (BF*)(ws + 37748736);       // M*128*2 = 4 MB
    float* part    = (float*)(ws + 41943040);    // 4*128*4
    float* g2      = (float*)(ws + 41945088);    // 4*128*4

    // 1. LN1 (NCHW -> bf16 NHWC rows; zeroes part)
    ln1_kernel<<<MTOT, 128, 0, stream>>>(x, ln1_w, ln1_b, xn_bf, part);
    // 2. conv1+gelu+conv2 fused -> t f32, + column sums into part
    conv_fused<<<256, 256, 0, stream>>>(xn_bf, conv1_w, conv1_b, conv2_w, conv2_b, t, part);
    // 3. channel-attention gate
    ca_kernel<<<NB, 128, 0, stream>>>(part, ca1_w, ca1_b, ca2_w, ca2_b, g2);
    // 4. qkv: (M,128)@(128,384) -> bf16
    gemm64<0,1><<<dim3(6, MTOT/64), 256, 0, stream>>>(xn_bf, qkv_w, qkv_b, qkv_bf, nullptr, MTOT, 384, 128);
    // 5. neighborhood attention
    na_tile_kernel<<<1024, 512, 0, stream>>>(qkv_bf, rpb, (unsigned*)na_bf);
    // 6. proj + x2 residual + LN2 fused
    projx2ln2<<<256, 256, 0, stream>>>(na_bf, proj_w, proj_b, x, t, g2, ln2_w, ln2_b, x2b, ln2_bf);
    // 7. fc1: (M,128)@(128,512)+gelu -> bf16 (overlays xn/qkv)
    gemm64<1,1><<<dim3(8, MTOT/64), 256, 0, stream>>>(ln2_bf, fc1_w, fc1_b, hbuf_bf, nullptr, MTOT, 512, 128);
    // 8. fc2: (M,512)@(512,128) + x2b, fused NHWC->NCHW store
    gemm64<0,2><<<dim3(2, MTOT/64), 256, 0, stream>>>(hbuf_bf, fc2_w, fc2_b, out, x2b, MTOT, 128, 512);
}

// Round 7
// 214.314 us; speedup vs baseline: 2.1294x; 1.0798x over previous
//
#include <hip/hip_runtime.h>
#include <hip/hip_bf16.h>
#include <math.h>

#define NB 4
#define CC 128
#define HH 64
#define WW 64
#define HEADS 4
#define KS 7
#define DD 32
#define HW 4096
#define MTOT 16384   // NB*HW

typedef unsigned short BF;
typedef short short8 __attribute__((ext_vector_type(8)));
typedef float floatx4 __attribute__((ext_vector_type(4)));

__device__ __forceinline__ float gelu_f(float x) {
    return 0.5f * x * (1.0f + erff(x * 0.70710678118654752440f));
}

__device__ __forceinline__ BF f2bf(float f) {
    union { float f; unsigned u; } a; a.f = f;
    unsigned u = a.u;
    unsigned r = u + 0x7FFFu + ((u >> 16) & 1u);   // RNE
    return (BF)(r >> 16);
}

__device__ __forceinline__ float bflo(unsigned p) { return __uint_as_float(p << 16); }
__device__ __forceinline__ float bfhi(unsigned p) { return __uint_as_float(p & 0xffff0000u); }

#define LDK 40      // padded LDS row, K=32 tiles (bf16)
#define LDK128 136  // padded LDS row, K=128 tiles (bf16)

// ---------------- LN1 transpose-tile: NCHW -> bf16 NHWC rows ----------
// block = 32 p x 128 c, coalesced 128B reads along p, LDS transpose,
// coalesced 256B bf16 row writes. grid 512.
__global__ __launch_bounds__(256) void ln1t_kernel(
    const float* __restrict__ x, const float* __restrict__ w,
    const float* __restrict__ b, BF* __restrict__ out,
    float* __restrict__ part)
{
    __shared__ float xt[128][33];
    __shared__ float mus[32], rss[32];
    const int blk = blockIdx.x;          // 0..511
    const int n  = blk >> 7;
    const int p0 = (blk & 127) * 32;
    const int t  = threadIdx.x;
    if (blk < 4 && t < 128) part[blk * CC + t] = 0.f;   // zero CA partials

    {   // stage: 8 c-rows per iter, 32 consecutive p per row (coalesced)
        int pp = t & 31, c8 = t >> 5;
        #pragma unroll 4
        for (int it = 0; it < 16; it++) {
            int c = it * 8 + c8;
            xt[c][pp] = x[(size_t)(n * CC + c) * HW + p0 + pp];
        }
    }
    __syncthreads();
    {   // LN stats: 8 lanes per p-row
        int pp2 = t >> 3, cb = t & 7;
        float s = 0.f;
        #pragma unroll
        for (int u = 0; u < 16; u++) s += xt[cb + u * 8][pp2];
        s += __shfl_xor(s, 1); s += __shfl_xor(s, 2); s += __shfl_xor(s, 4);
        float mu = s * (1.0f / CC);
        float v = 0.f;
        #pragma unroll
        for (int u = 0; u < 16; u++) { float d = xt[cb + u * 8][pp2] - mu; v += d * d; }
        v += __shfl_xor(v, 1); v += __shfl_xor(v, 2); v += __shfl_xor(v, 4);
        if (cb == 0) { mus[pp2] = mu; rss[pp2] = rsqrtf(v * (1.0f / CC) + 1e-5f); }
    }
    __syncthreads();
    {   // write: 16 lanes x 16B = 256B per row, 2 iters over 32 p
        #pragma unroll
        for (int it = 0; it < 2; it++) {
            int pp2 = (t >> 4) + it * 16;
            int c0  = (t & 15) * 8;
            float mu = mus[pp2], rs = rss[pp2];
            int m = n * HW + p0 + pp2;
            short8 o;
            #pragma unroll
            for (int u = 0; u < 8; u++)
                o[u] = (short)f2bf((xt[c0 + u][pp2] - mu) * rs * w[c0 + u] + b[c0 + u]);
            *(short8*)(out + (size_t)m * CC + c0) = o;
        }
    }
}

// ---------------- K=128 barrier-lean GEMM body ------------------------
// B (128,N) f32 staged fully to LDS once; A bf16 fragments loaded direct
// from global (row-major, K contiguous). One barrier total.
template<int ACT>
__device__ __forceinline__ void k128_body(
    const BF* __restrict__ A, const float* __restrict__ B,
    const float* __restrict__ bias, BF* __restrict__ Cout,
    int N, int row0, int col0, BF* Bl /* [64][LDK128] */)
{
    const int t = threadIdx.x;
    const int w = t >> 6, lane = t & 63, q = lane >> 4, r16 = lane & 15;
    {   // stage B slice 128x64 -> [n][k]
        int kk = t >> 1, nn0 = (t & 1) * 32;
        const float* src = B + (size_t)kk * N + col0 + nn0;
        #pragma unroll
        for (int u = 0; u < 32; u++) Bl[(nn0 + u) * LDK128 + kk] = f2bf(src[u]);
    }
    __syncthreads();
    floatx4 acc[4] = {};
    const BF* arow = A + (size_t)(row0 + w * 16 + r16) * CC;
    #pragma unroll
    for (int ks = 0; ks < 4; ks++) {
        short8 af = *(const short8*)(arow + ks * 32 + q * 8);
        #pragma unroll
        for (int nt = 0; nt < 4; nt++) {
            short8 bf = *(const short8*)(Bl + (nt * 16 + r16) * LDK128 + ks * 32 + q * 8);
            acc[nt] = __builtin_amdgcn_mfma_f32_16x16x32_bf16(af, bf, acc[nt], 0, 0, 0);
        }
    }
    #pragma unroll
    for (int nt = 0; nt < 4; nt++) {
        int col = col0 + nt * 16 + r16;
        float bv = bias[col];
        #pragma unroll
        for (int reg = 0; reg < 4; reg++) {
            int row = row0 + w * 16 + q * 4 + reg;
            float v = acc[nt][reg] + bv;
            if (ACT == 1) v = gelu_f(v);
            Cout[(size_t)row * N + col] = f2bf(v);
        }
    }
}

// ---------------- phase2: qkv GEMM blocks + conv-MLP blocks -----------
// blocks [0,1536): qkv (M,128)@(128,384) -> bf16
// blocks [1536,1792): conv1+gelu+conv2 -> t f32 + column sums into part
__global__ __launch_bounds__(256) void phase2(
    const BF* __restrict__ xn, const float* __restrict__ qkv_w,
    const float* __restrict__ qkv_b, BF* __restrict__ qkv_out,
    const float* __restrict__ w1, const float* __restrict__ b1,
    const float* __restrict__ w2, const float* __restrict__ b2,
    float* __restrict__ tout, float* __restrict__ part)
{
    __shared__ __align__(16) char smem[26624];
    const int bid = blockIdx.x;
    const int t = threadIdx.x;
    const int w = t >> 6, lane = t & 63, q = lane >> 4, r16 = lane & 15;

    if (bid < 1536) {
        int col0 = (bid % 6) * 64;
        int row0 = (bid / 6) * 64;
        k128_body<0>(xn, qkv_w, qkv_b, qkv_out, 384, row0, col0, (BF*)smem);
        return;
    }
    // ---- conv branch ----
    BF*    W1l = (BF*)smem;                  // [32][LDK128]  8704 B
    BF*    W2l = (BF*)(smem + 8704);         // [128][LDK]   10240 B
    BF*    Hl  = (BF*)(smem + 18944);        // [64][LDK]     5120 B
    float* red = (float*)(smem + 24064);     // [4][128]      2048 B
    const int row0 = (bid - 1536) * 64;
    {   // stage W1 (128,32) -> [n][k]
        int kk = t >> 1, nn = (t & 1) * 16;
        const float* src = w1 + (size_t)kk * 32 + nn;
        #pragma unroll
        for (int u = 0; u < 16; u++) W1l[(nn + u) * LDK128 + kk] = f2bf(src[u]);
    }
    {   // stage W2 (32,128) -> [n][k]
        int kk = t >> 3, n0 = (t & 7) * 16;
        const float* src = w2 + (size_t)kk * 128 + n0;
        #pragma unroll
        for (int u = 0; u < 16; u++) W2l[(n0 + u) * LDK + kk] = f2bf(src[u]);
    }
    __syncthreads();
    // stage 1: h = gelu(X @ w1 + b1), A direct from global
    floatx4 a1[2] = {};
    const BF* arow = xn + (size_t)(row0 + w * 16 + r16) * CC;
    #pragma unroll
    for (int ks = 0; ks < 4; ks++) {
        short8 af = *(const short8*)(arow + ks * 32 + q * 8);
        #pragma unroll
        for (int nt = 0; nt < 2; nt++) {
            short8 bf = *(const short8*)(W1l + (nt * 16 + r16) * LDK128 + ks * 32 + q * 8);
            a1[nt] = __builtin_amdgcn_mfma_f32_16x16x32_bf16(af, bf, a1[nt], 0, 0, 0);
        }
    }
    #pragma unroll
    for (int nt = 0; nt < 2; nt++) {
        int col = nt * 16 + r16;
        float bv = b1[col];
        #pragma unroll
        for (int reg = 0; reg < 4; reg++)
            Hl[(w * 16 + q * 4 + reg) * LDK + col] = f2bf(gelu_f(a1[nt][reg] + bv));
    }
    __syncthreads();
    // stage 2: t = H @ w2 + b2 (K=32) + column sums
    floatx4 a2[8] = {};
    short8 af2 = *(const short8*)(Hl + (w * 16 + r16) * LDK + q * 8);
    #pragma unroll
    for (int nt = 0; nt < 8; nt++) {
        short8 bf = *(const short8*)(W2l + (nt * 16 + r16) * LDK + q * 8);
        a2[nt] = __builtin_amdgcn_mfma_f32_16x16x32_bf16(af2, bf, a2[nt], 0, 0, 0);
    }
    #pragma unroll
    for (int nt = 0; nt < 8; nt++) {
        int col = nt * 16 + r16;
        float bv = b2[col];
        float s = 0.f;
        #pragma unroll
        for (int reg = 0; reg < 4; reg++) {
            int row = row0 + w * 16 + q * 4 + reg;
            float v = a2[nt][reg] + bv;
            tout[(size_t)row * CC + col] = v;
            s += v;
        }
        s += __shfl_xor(s, 16);
        s += __shfl_xor(s, 32);
        if (lane < 16) red[w * 128 + col] = s;
    }
    __syncthreads();
    if (t < 128) {
        float cs = red[t] + red[128 + t] + red[256 + t] + red[384 + t];
        atomicAdd(&part[(row0 >> 12) * CC + t], cs);
    }
}

// ---------------- standalone K=128 GEMM (fc1) -------------------------
template<int ACT>
__global__ __launch_bounds__(256) void gemm_k128(
    const BF* __restrict__ A, const float* __restrict__ B,
    const float* __restrict__ bias, BF* __restrict__ Cout, int N)
{
    __shared__ __align__(16) BF Bl[64 * LDK128];
    k128_body<ACT>(A, B, bias, Cout, N, blockIdx.y * 64, blockIdx.x * 64, Bl);
}

// ---------------- gemm64 (K-loop version; used for fc2, K=512) --------
// OUT: 2 = NCHW final (C = acc+bias+x2b, transposed store)
template<int ACT, int OUT>
__global__ __launch_bounds__(256) void gemm64(
    const BF* __restrict__ A, const float* __restrict__ B,
    const float* __restrict__ bias, void* __restrict__ Cout,
    const float* __restrict__ x2b,
    int M, int N, int K)
{
    __shared__ __align__(16) BF Alds[64][LDK];
    __shared__ __align__(16) BF Blds[64][LDK];   // [n][k]

    const int t    = threadIdx.x;
    const int w    = t >> 6;
    const int lane = t & 63;
    const int q    = lane >> 4;
    const int r16  = lane & 15;
    const int row0 = blockIdx.y * 64;
    const int col0 = blockIdx.x * 64;

    floatx4 acc[4] = {};
    const int ar = t >> 2;
    const int ak = (t & 3) * 8;
    const int bk = t >> 3;
    const int bn = (t & 7) * 8;

    for (int k0 = 0; k0 < K; k0 += 32) {
        *(short8*)(&Alds[ar][ak]) =
            *(const short8*)(A + (size_t)(row0 + ar) * K + k0 + ak);
        {
            const float* src = B + (size_t)(k0 + bk) * N + col0 + bn;
            float4 b0 = *(const float4*)(src);
            float4 b1 = *(const float4*)(src + 4);
            Blds[bn + 0][bk] = f2bf(b0.x); Blds[bn + 1][bk] = f2bf(b0.y);
            Blds[bn + 2][bk] = f2bf(b0.z); Blds[bn + 3][bk] = f2bf(b0.w);
            Blds[bn + 4][bk] = f2bf(b1.x); Blds[bn + 5][bk] = f2bf(b1.y);
            Blds[bn + 6][bk] = f2bf(b1.z); Blds[bn + 7][bk] = f2bf(b1.w);
        }
        __syncthreads();
        short8 af = *(const short8*)(&Alds[w * 16 + r16][q * 8]);
        short8 bfm[4];
        #pragma unroll
        for (int nt = 0; nt < 4; nt++)
            bfm[nt] = *(const short8*)(&Blds[nt * 16 + r16][q * 8]);
        #pragma unroll
        for (int nt = 0; nt < 4; nt++)
            acc[nt] = __builtin_amdgcn_mfma_f32_16x16x32_bf16(af, bfm[nt], acc[nt], 0, 0, 0);
        __syncthreads();
    }

    #pragma unroll
    for (int nt = 0; nt < 4; nt++) {
        int col = col0 + nt * 16 + r16;
        float bv = bias[col];
        #pragma unroll
        for (int reg = 0; reg < 4; reg++) {
            int row = row0 + w * 16 + q * 4 + reg;
            float v = acc[nt][reg] + bv;
            if (ACT == 1) v = gelu_f(v);
            if (OUT == 2) {
                int p = row & 4095, n = row >> 12;
                ((float*)Cout)[(size_t)(n * CC + col) * HW + p] =
                    v + x2b[(size_t)row * CC + col];
            } else {
                ((float*)Cout)[(size_t)row * N + col] = v;
            }
        }
    }
}

// ---------------- tiled neighborhood attention (bf16 qkv in/out) ------
__global__ __launch_bounds__(512) void na_tile_kernel(
    const BF* __restrict__ qkv, const float* __restrict__ rpb,
    unsigned* __restrict__ outp)
{
    __shared__ unsigned Kb32[16][210];
    __shared__ unsigned Vb32[196][16];
    __shared__ unsigned Qb32[64][16];
    __shared__ float rb[169];
    __shared__ float sp[8][64];

    const int b    = blockIdx.x;
    const int h    = b & 3;
    const int tile = b >> 2;
    const int n    = tile >> 6;
    const int ti   = (tile >> 3) & 7;
    const int tj   = tile & 7;
    const int t    = threadIdx.x;
    const int w    = t >> 6;
    const int lane = t & 63;

    const int i0 = ti * 8, j0 = tj * 8;
    const int wi0 = max(i0 - 3, 0);
    const int wj0 = max(j0 - 3, 0);
    const int R  = min(wi0 + 13, HH - 1) - wi0 + 1;
    const int Rj = min(wj0 + 13, WW - 1) - wj0 + 1;

    for (int idx = t; idx < 196 * 8; idx += 512) {
        int pixel = idx >> 3, ch = idx & 7;
        int pr = pixel / 14, pc = pixel % 14;
        if (pr < R && pc < Rj) {
            int seg = ch >> 2, c4 = ch & 3;
            const BF* src = qkv
                + ((size_t)((n * HH + wi0 + pr) * WW + wj0 + pc)) * 384
                + 128 + seg * 128 + h * DD + c4 * 8;
            uint4 v = *(const uint4*)src;
            if (seg == 0) {
                Kb32[c4 * 4 + 0][pixel] = v.x;
                Kb32[c4 * 4 + 1][pixel] = v.y;
                Kb32[c4 * 4 + 2][pixel] = v.z;
                Kb32[c4 * 4 + 3][pixel] = v.w;
            } else {
                *(uint4*)&Vb32[pixel][c4 * 4] = v;
            }
        }
    }
    for (int idx = t; idx < 64 * 4; idx += 512) {
        int q = idx >> 2, c4 = idx & 3;
        int qi = q >> 3, qj = q & 7;
        size_t m = (size_t)((n * HH + i0 + qi) * WW + j0 + qj);
        *(uint4*)&Qb32[q][c4 * 4] = *(const uint4*)(qkv + m * 384 + h * DD + c4 * 8);
    }
    if (t < 169) rb[t] = rpb[h * 169 + t];
    __syncthreads();

    for (int qq = 0; qq < 8; qq++) {
        int q  = w * 8 + qq;
        int qi = q >> 3, qj = q & 7;
        int i = i0 + qi, j = j0 + qj;
        int ni = min(max(i - 3, 0), HH - KS);
        int nj = min(max(j - 3, 0), WW - KS);
        int keybase = (ni - wi0) * 14 + (nj - wj0);

        unsigned qp[16];
        #pragma unroll
        for (int u = 0; u < 16; u++) qp[u] = Qb32[q][u];

        int aa = min(lane, KS * KS - 1);
        int ar = aa / KS, ac = aa % KS;
        int key = keybase + ar * 14 + ac;
        float s = 0.f;
        #pragma unroll
        for (int dp = 0; dp < 16; dp++) {
            unsigned kv = Kb32[dp][key];
            s += bflo(qp[dp]) * bflo(kv);
            s += bfhi(qp[dp]) * bfhi(kv);
        }
        s = s * 0.17677669529663688110f + rb[(ni - i + 6 + ar) * 13 + (nj - j + 6 + ac)];
        float score = (lane < KS * KS) ? s : -INFINITY;

        float mx = score;
        #pragma unroll
        for (int off = 32; off; off >>= 1) mx = fmaxf(mx, __shfl_xor(mx, off));
        float e = (lane < KS * KS) ? __expf(score - mx) : 0.f;
        float sm = e;
        #pragma unroll
        for (int off = 32; off; off >>= 1) sm += __shfl_xor(sm, off);
        sp[w][lane] = e / sm;

        int quarter = lane >> 4, dpv = lane & 15;
        float accl = 0.f, acch = 0.f;
        int rr = 0, cc = quarter;
        #pragma unroll
        for (int it = 0; it < 13; it++) {
            int a4 = 4 * it + quarter;
            if (a4 < 49) {
                float p = sp[w][a4];
                unsigned pv = Vb32[keybase + rr * 14 + cc][dpv];
                accl += p * bflo(pv);
                acch += p * bfhi(pv);
            }
            cc += 4; if (cc >= KS) { cc -= KS; rr++; }
        }
        accl += __shfl_xor(accl, 16); accl += __shfl_xor(accl, 32);
        acch += __shfl_xor(acch, 16); acch += __shfl_xor(acch, 32);
        if (lane < 16) {
            size_t m = (size_t)((n * HH + i) * WW + j);
            unsigned pk = ((unsigned)f2bf(accl)) | (((unsigned)f2bf(acch)) << 16);
            outp[m * 64 + h * 16 + dpv] = pk;
        }
    }
}

// ---------------- fused CA-gate + proj GEMM + x2 residual + LN2 -------
// Row-complete (BM=64, BN=128). Gate g computed in-block from part.
__global__ __launch_bounds__(256) void projx2ln2g(
    const BF* __restrict__ A, const float* __restrict__ Bw,
    const float* __restrict__ bias, const float* __restrict__ x,
    const float* __restrict__ tbuf, const float* __restrict__ part,
    const float* __restrict__ ca1_w, const float* __restrict__ ca1_b,
    const float* __restrict__ ca2_w, const float* __restrict__ ca2_b,
    const float* __restrict__ w2, const float* __restrict__ b2,
    float* __restrict__ x2b, BF* __restrict__ lnout)
{
    __shared__ __align__(16) BF Bl[128 * LDK128];   // 34816 B
    __shared__ float gs[128];
    __shared__ float h1[7];
    __shared__ float gl[128];

    const int t = threadIdx.x;
    const int w = t >> 6, lane = t & 63, q = lane >> 4, r16 = lane & 15;
    const int row0 = blockIdx.x * 64;
    const int n = row0 >> 12;

    {   // stage proj_w (128x128) fully
        int kk = t >> 1, nn0 = (t & 1) * 64;
        const float* src = Bw + (size_t)kk * CC + nn0;
        #pragma unroll
        for (int u = 0; u < 64; u++) Bl[(nn0 + u) * LDK128 + kk] = f2bf(src[u]);
    }
    if (t < 128) gs[t] = part[n * CC + t] * (1.0f / HW);
    __syncthreads();
    if (t < 7) {
        float a = ca1_b[t];
        for (int k = 0; k < 128; k++) a += gs[k] * ca1_w[k * 7 + t];
        h1[t] = fmaxf(a, 0.f);
    }
    __syncthreads();
    if (t < 128) {
        float o = ca2_b[t];
        #pragma unroll
        for (int r = 0; r < 7; r++) o += h1[r] * ca2_w[r * 128 + t];
        gl[t] = 1.0f / (1.0f + expf(-o));
    }

    floatx4 acc[8] = {};
    const BF* arow = A + (size_t)(row0 + w * 16 + r16) * CC;
    #pragma unroll
    for (int ks = 0; ks < 4; ks++) {
        short8 af = *(const short8*)(arow + ks * 32 + q * 8);
        #pragma unroll
        for (int nt = 0; nt < 8; nt++) {
            short8 bf = *(const short8*)(Bl + (nt * 16 + r16) * LDK128 + ks * 32 + q * 8);
            acc[nt] = __builtin_amdgcn_mfma_f32_16x16x32_bf16(af, bf, acc[nt], 0, 0, 0);
        }
    }
    __syncthreads();   // gl visible to all

    float s1[4] = {0.f, 0.f, 0.f, 0.f}, s2[4] = {0.f, 0.f, 0.f, 0.f};
    #pragma unroll
    for (int nt = 0; nt < 8; nt++) {
        int col = nt * 16 + r16;
        float bv = bias[col];
        float gv = gl[col];
        #pragma unroll
        for (int reg = 0; reg < 4; reg++) {
            int row = row0 + w * 16 + q * 4 + reg;
            int p = row & 4095;
            float xv = x[(size_t)(n * CC + col) * HW + p];
            float tv = tbuf[(size_t)row * CC + col];
            float v = acc[nt][reg] + bv + xv + 0.02f * tv * gv;
            acc[nt][reg] = v;
            s1[reg] += v;
            s2[reg] += v * v;
        }
    }
    #pragma unroll
    for (int reg = 0; reg < 4; reg++) {
        #pragma unroll
        for (int off = 8; off; off >>= 1) {
            s1[reg] += __shfl_xor(s1[reg], off);
            s2[reg] += __shfl_xor(s2[reg], off);
        }
    }
    float mu[4], rr[4];
    #pragma unroll
    for (int reg = 0; reg < 4; reg++) {
        mu[reg] = s1[reg] * (1.0f / CC);
        float var = s2[reg] * (1.0f / CC) - mu[reg] * mu[reg];
        rr[reg] = rsqrtf(var + 1e-5f);
    }
    #pragma unroll
    for (int nt = 0; nt < 8; nt++) {
        int col = nt * 16 + r16;
        float wv = w2[col], bv2 = b2[col];
        #pragma unroll
        for (int reg = 0; reg < 4; reg++) {
            int row = row0 + w * 16 + q * 4 + reg;
            float v = acc[nt][reg];
            x2b[(size_t)row * CC + col] = v;
            lnout[(size_t)row * CC + col] = f2bf((v - mu[reg]) * rr[reg] * wv + bv2);
        }
    }
}

extern "C" void kernel_launch(void* const* d_in, const int* in_sizes, int n_in,
                              void* d_out, int out_size, void* d_ws, size_t ws_size,
                              hipStream_t stream)
{
    const float* x       = (const float*)d_in[0];
    const float* ln1_w   = (const float*)d_in[1];
    const float* ln1_b   = (const float*)d_in[2];
    const float* ln2_w   = (const float*)d_in[3];
    const float* ln2_b   = (const float*)d_in[4];
    const float* qkv_w   = (const float*)d_in[5];
    const float* qkv_b   = (const float*)d_in[6];
    const float* proj_w  = (const float*)d_in[7];
    const float* proj_b  = (const float*)d_in[8];
    const float* rpb     = (const float*)d_in[9];
    const float* conv1_w = (const float*)d_in[10];
    const float* conv1_b = (const float*)d_in[11];
    const float* conv2_w = (const float*)d_in[12];
    const float* conv2_b = (const float*)d_in[13];
    const float* ca1_w   = (const float*)d_in[14];
    const float* ca1_b   = (const float*)d_in[15];
    const float* ca2_w   = (const float*)d_in[16];
    const float* ca2_b   = (const float*)d_in[17];
    const float* fc1_w   = (const float*)d_in[18];
    const float* fc1_b   = (const float*)d_in[19];
    const float* fc2_w   = (const float*)d_in[20];
    const float* fc2_b   = (const float*)d_in[21];
    float* out = (float*)d_out;

    // workspace (bytes). hbuf_bf overlays xn_bf+qkv_bf (both dead by fc1).
    char* ws = (char*)d_ws;
    BF*    xn_bf   = (BF*)(ws);                  // M*128*2 = 4 MB
    BF*    qkv_bf  = (BF*)(ws + 4194304);        // M*384*2 = 12 MB
    BF*    hbuf_bf = (BF*)(ws);                  // M*512*2 = 16 MB (overlay)
    float* t       = (float*)(ws + 16777216);    // M*128*4 = 8 MB
    float* x2b     = (float*)(ws + 25165824);    // M*128*4 = 8 MB
    BF*    na_bf   = (BF*)(ws + 33554432);       // M*128*2 = 4 MB
    BF*    ln2_bf  = (BF*)(ws + 37748736);       // M*128*2 = 4 MB
    float* part    = (float*)(ws + 41943040);    // 4*128*4

    // 1. LN1 transpose-tile (coalesced NCHW read; zeroes part)
    ln1t_kernel<<<512, 256, 0, stream>>>(x, ln1_w, ln1_b, xn_bf, part);
    // 2. qkv GEMM + conv-MLP (+column sums), one launch
    phase2<<<1792, 256, 0, stream>>>(xn_bf, qkv_w, qkv_b, qkv_bf,
                                     conv1_w, conv1_b, conv2_w, conv2_b, t, part);
    // 3. neighborhood attention
    na_tile_kernel<<<1024, 512, 0, stream>>>(qkv_bf, rpb, (unsigned*)na_bf);
    // 4. CA gate + proj + x2 residual + LN2, one launch
    projx2ln2g<<<256, 256, 0, stream>>>(na_bf, proj_w, proj_b, x, t, part,
                                        ca1_w, ca1_b, ca2_w, ca2_b,
                                        ln2_w, ln2_b, x2b, ln2_bf);
    // 5. fc1: (M,128)@(128,512)+gelu -> bf16 (overlays xn/qkv)
    gemm_k128<1><<<dim3(8, 256), 256, 0, stream>>>(ln2_bf, fc1_w, fc1_b, hbuf_bf, 512);
    // 6. fc2: (M,512)@(512,128) + x2b, fused NHWC->NCHW store
    gemm64<0,2><<<dim3(2, 256), 256, 0, stream>>>(hbuf_bf, fc2_w, fc2_b, out, x2b, MTOT, 128, 512);
}